// Round 16
// baseline (1756.577 us; speedup 1.0000x reference)
//
#include <hip/hip_runtime.h>
#include <hip/hip_bf16.h>

#define LAT 128
#define LATP 132   // padded fp32 LDS row stride -> reduced-conflict MFMA A-reads
#define EPS 1e-5f
#define EB 32
#define TS 136     // bf16 tile row stride in shorts

typedef __attribute__((ext_vector_type(8))) short bs8;
typedef __attribute__((ext_vector_type(4))) float fx4;

__device__ __forceinline__ float bf2f(unsigned int u) {
    return __uint_as_float(u << 16);
}
// native RNE f32 -> bf16 (register-only use)
__device__ __forceinline__ unsigned short f2bf(float f) {
    union { __hip_bfloat16 b; unsigned short u; } cv;
    cv.b = __float2bfloat16(f);
    return cv.u;
}
__device__ __forceinline__ void unpack8(uint4 u, float* v) {
    v[0] = bf2f(u.x & 0xffffu); v[1] = bf2f(u.x >> 16);
    v[2] = bf2f(u.y & 0xffffu); v[3] = bf2f(u.y >> 16);
    v[4] = bf2f(u.z & 0xffffu); v[5] = bf2f(u.z >> 16);
    v[6] = bf2f(u.w & 0xffffu); v[7] = bf2f(u.w >> 16);
}
__device__ __forceinline__ uint4 pack8(const float* v) {
    uint4 u;
    u.x = (unsigned)f2bf(v[0]) | ((unsigned)f2bf(v[1]) << 16);
    u.y = (unsigned)f2bf(v[2]) | ((unsigned)f2bf(v[3]) << 16);
    u.z = (unsigned)f2bf(v[4]) | ((unsigned)f2bf(v[5]) << 16);
    u.w = (unsigned)f2bf(v[6]) | ((unsigned)f2bf(v[7]) << 16);
    return u;
}
// fp32 LDS -> bf16 A-fragment: EXPLICIT float4 loads (2x ds_read_b128, r13
// access pattern) + native cvt from registers (r15 ALU saving).
__device__ __forceinline__ bs8 cvt8(const float* p) {
    float4 f0 = *(const float4*)p;
    float4 f1 = *(const float4*)(p + 4);
    bs8 r;
    r[0] = (short)f2bf(f0.x); r[1] = (short)f2bf(f0.y);
    r[2] = (short)f2bf(f0.z); r[3] = (short)f2bf(f0.w);
    r[4] = (short)f2bf(f1.x); r[5] = (short)f2bf(f1.y);
    r[6] = (short)f2bf(f1.z); r[7] = (short)f2bf(f1.w);
    return r;
}

__global__ __launch_bounds__(256) void zero_kernel(float4* __restrict__ p, int n4) {
    int i = blockIdx.x * 256 + threadIdx.x;
    if (i < n4) p[i] = make_float4(0.f, 0.f, 0.f, 0.f);
}

// ---------------------------------------------------------------------------
// C/D-map probe (pi-invariant), VALIDATED round 8.
// ---------------------------------------------------------------------------
__global__ void probe_kernel(int* __restrict__ rowtab, int* __restrict__ coltab) {
    int l = threadIdx.x;
    bs8 idv, ones;
    unsigned short ridb = f2bf((float)(l & 15));
    unsigned short oneb = f2bf(1.f);
    #pragma unroll
    for (int i = 0; i < 8; i++) { idv[i] = (short)ridb; ones[i] = (short)oneb; }
    fx4 dR = {0.f, 0.f, 0.f, 0.f};
    fx4 dC = {0.f, 0.f, 0.f, 0.f};
    dR = __builtin_amdgcn_mfma_f32_16x16x32_bf16(idv, ones, dR, 0, 0, 0);
    dC = __builtin_amdgcn_mfma_f32_16x16x32_bf16(ones, idv, dC, 0, 0, 0);
    #pragma unroll
    for (int reg = 0; reg < 4; reg++) {
        rowtab[l * 4 + reg] = ((int)(dR[reg] * (1.f / 32.f) + 0.5f)) & 15;
        coltab[l * 4 + reg] = ((int)(dC[reg] * (1.f / 32.f) + 0.5f)) & 15;
    }
}

// Pack fp32 weight [K=KS*32][128] into MFMA B-fragment order, bf16. VALIDATED r8.
__global__ __launch_bounds__(256) void pack_w_kernel(
    const float* __restrict__ src, unsigned short* __restrict__ dst, int KS)
{
    int id = blockIdx.x * 256 + threadIdx.x;
    if (id >= KS * 4096) return;
    int j = id & 7;
    int l = (id >> 3) & 63;
    int rest = id >> 9;
    int ks = rest % KS, nt = rest / KS;
    int k = ks * 32 + (l >> 4) * 8 + j;
    int n = nt * 16 + (l & 15);
    dst[id] = f2bf(src[k * 128 + n]);
}

// ---------------------------------------------------------------------------
// HYBRID encoder (r13 validated): VALU L1 -> fp32 LDS -> MFMA L2 -> LN.
// ---------------------------------------------------------------------------
template<int KIN>
__global__ __launch_bounds__(256, 4) void encode_hybrid(
    const float* __restrict__ x, unsigned short* __restrict__ out,
    const float* __restrict__ w1, const float* __restrict__ b1,
    const unsigned short* __restrict__ w2p, const float* __restrict__ b2,
    const float* __restrict__ gam, const float* __restrict__ bet,
    const int* __restrict__ rowtab, const int* __restrict__ coltab, int M)
{
    __shared__ float l1f[EB][LATP];

    const int t = threadIdx.x;
    const int base = blockIdx.x * EB;
    const int j = t & 127, g = t >> 7;

    float wv[KIN];
    #pragma unroll
    for (int u = 0; u < KIN; u++) wv[u] = w1[u * LAT + j];
    const float bb = b1[j];
    #pragma unroll
    for (int i = 0; i < 16; i++) {
        int r = g + 2 * i; int row = base + r;
        float acc = bb;
        if (row < M) {
            #pragma unroll
            for (int u = 0; u < KIN; u++) acc += x[(size_t)row * KIN + u] * wv[u];
        }
        l1f[r][j] = fmaxf(acc, 0.f);
    }
    __syncthreads();

    const int wid = t >> 6, lane = t & 63;
    const int r15 = lane & 15, q = lane >> 4;

    int4 rt = *(const int4*)(rowtab + lane * 4);
    int4 ct = *(const int4*)(coltab + lane * 4);
    int rl4[4] = {rt.x, rt.y, rt.z, rt.w};
    int cl4[4] = {ct.x, ct.y, ct.z, ct.w};

    fx4 a2[2][2];
    #pragma unroll
    for (int mt = 0; mt < 2; mt++)
        #pragma unroll
        for (int nt = 0; nt < 2; nt++) { fx4 z = {0.f, 0.f, 0.f, 0.f}; a2[mt][nt] = z; }

    #pragma unroll
    for (int kc = 0; kc < 4; kc++) {
        bs8 bf0 = *(const bs8*)(w2p + (((size_t)(wid * 2 + 0) * 4 + kc) * 64 + lane) * 8);
        bs8 bf1 = *(const bs8*)(w2p + (((size_t)(wid * 2 + 1) * 4 + kc) * 64 + lane) * 8);
        #pragma unroll
        for (int mt = 0; mt < 2; mt++) {
            int row = mt * 16 + r15;
            int k0 = kc * 32 + q * 8;
            bs8 a = cvt8(&l1f[row][k0]);
            a2[mt][0] = __builtin_amdgcn_mfma_f32_16x16x32_bf16(a, bf0, a2[mt][0], 0, 0, 0);
            a2[mt][1] = __builtin_amdgcn_mfma_f32_16x16x32_bf16(a, bf1, a2[mt][1], 0, 0, 0);
        }
    }
    __syncthreads();

    #pragma unroll
    for (int nt = 0; nt < 2; nt++) {
        #pragma unroll
        for (int reg = 0; reg < 4; reg++) {
            int cg = (wid * 2 + nt) * 16 + cl4[reg];
            float bv = b2[cg];
            #pragma unroll
            for (int mt = 0; mt < 2; mt++) {
                int row = mt * 16 + rl4[reg];
                l1f[row][cg] = fmaxf(a2[mt][nt][reg] + bv, 0.f);
            }
        }
    }
    __syncthreads();

    const float g0 = gam[lane], g1 = gam[lane + 64];
    const float be0 = bet[lane], be1 = bet[lane + 64];
    #pragma unroll
    for (int which = 0; which < 8; which++) {
        int row = wid * 8 + which;
        int rowg = base + row;
        float v0 = l1f[row][lane], v1 = l1f[row][lane + 64];
        float s1 = v0 + v1, sq = v0 * v0 + v1 * v1;
        #pragma unroll
        for (int m = 32; m >= 1; m >>= 1) { s1 += __shfl_xor(s1, m); sq += __shfl_xor(sq, m); }
        float mu = s1 * (1.f / LAT);
        float var = sq * (1.f / LAT) - mu * mu;
        float inv = rsqrtf(var + EPS);
        if (rowg < M) {
            out[(size_t)rowg * LAT + lane]      = f2bf((v0 - mu) * inv * g0 + be0);
            out[(size_t)rowg * LAT + lane + 64] = f2bf((v1 - mu) * inv * g1 + be1);
        }
    }
}

// ---------------------------------------------------------------------------
// Edge step (r13 validated): LDS union (hd/hs -> l1m/l1n) -> 34KB -> 4 blk/CU.
// ev direct from global. MFMA L1 dual + MFMA L2 (cvt8).
// ---------------------------------------------------------------------------
__global__ __launch_bounds__(256, 4) void edge_step_hybrid(
    const unsigned short* __restrict__ h, unsigned short* __restrict__ e_buf,
    float* __restrict__ agg, const int* __restrict__ ei,
    const unsigned short* __restrict__ w1p, const unsigned short* __restrict__ w2p,
    const float* __restrict__ b1, const float* __restrict__ b2,
    const float* __restrict__ gam, const float* __restrict__ bet,
    const int* __restrict__ rowtab, const int* __restrict__ coltab, int E)
{
    __shared__ __align__(16) float poolf[2 * EB * LATP];   // 33.8KB union
    __shared__ int sd[EB], ss[EB];
    unsigned short* hd = (unsigned short*)poolf;
    unsigned short* hs = (unsigned short*)poolf + EB * TS;
    float (*l1m)[LATP] = (float(*)[LATP])poolf;
    float (*l1n)[LATP] = (float(*)[LATP])(poolf + EB * LATP);

    const int t = threadIdx.x;
    const int base = blockIdx.x * EB;
    if (t < EB) {
        int ge = base + t;
        sd[t] = (ge < E) ? ei[E + ge] : 0;  // dst
        ss[t] = (ge < E) ? ei[ge] : 0;      // src
    }
    __syncthreads();

    for (int idx = t; idx < 2 * EB * 16; idx += 256) {
        int seg = idx / (EB * 16);
        int rem = idx - seg * (EB * 16);
        int r = rem >> 4, c = rem & 15;
        int ge = base + r;
        uint4 v = make_uint4(0, 0, 0, 0);
        if (ge < E) {
            const unsigned short* src = h + (size_t)(seg == 0 ? sd[r] : ss[r]) * LAT;
            v = *(const uint4*)(src + c * 8);
        }
        unsigned short* dstT = (seg == 0) ? hd : hs;
        *(uint4*)&dstT[r * TS + c * 8] = v;
    }
    __syncthreads();

    const int wid = t >> 6, lane = t & 63;
    const int r15 = lane & 15, q = lane >> 4;

    int4 rt = *(const int4*)(rowtab + lane * 4);
    int4 ct = *(const int4*)(coltab + lane * 4);
    int rl4[4] = {rt.x, rt.y, rt.z, rt.w};
    int cl4[4] = {ct.x, ct.y, ct.z, ct.w};

    // ---- MFMA layer 1, dual accumulators, shared ev@WB (ev from global) ----
    fx4 accm[2][2], accn[2][2];
    #pragma unroll
    for (int mt = 0; mt < 2; mt++)
        #pragma unroll
        for (int nt = 0; nt < 2; nt++) { fx4 z = {0.f, 0.f, 0.f, 0.f}; accm[mt][nt] = z; }

    #pragma unroll
    for (int kc = 0; kc < 4; kc++) {
        int ks = 8 + kc;
        bs8 bf0 = *(const bs8*)(w1p + (((size_t)(wid * 2 + 0) * 12 + ks) * 64 + lane) * 8);
        bs8 bf1 = *(const bs8*)(w1p + (((size_t)(wid * 2 + 1) * 12 + ks) * 64 + lane) * 8);
        #pragma unroll
        for (int mt = 0; mt < 2; mt++) {
            bs8 ae = *(const bs8*)(e_buf + (size_t)(base + mt * 16 + r15) * LAT + kc * 32 + q * 8);
            accm[mt][0] = __builtin_amdgcn_mfma_f32_16x16x32_bf16(ae, bf0, accm[mt][0], 0, 0, 0);
            accm[mt][1] = __builtin_amdgcn_mfma_f32_16x16x32_bf16(ae, bf1, accm[mt][1], 0, 0, 0);
        }
    }
    #pragma unroll
    for (int mt = 0; mt < 2; mt++) { accn[mt][0] = accm[mt][0]; accn[mt][1] = accm[mt][1]; }

    #pragma unroll
    for (int ts = 0; ts < 2; ts++) {
        const unsigned short* tA = ts ? hs : hd;
        const unsigned short* tB = ts ? hd : hs;
        #pragma unroll
        for (int kc = 0; kc < 4; kc++) {
            int ks = ts * 4 + kc;
            bs8 bf0 = *(const bs8*)(w1p + (((size_t)(wid * 2 + 0) * 12 + ks) * 64 + lane) * 8);
            bs8 bf1 = *(const bs8*)(w1p + (((size_t)(wid * 2 + 1) * 12 + ks) * 64 + lane) * 8);
            #pragma unroll
            for (int mt = 0; mt < 2; mt++) {
                int aoff = (mt * 16 + r15) * TS + kc * 32 + q * 8;
                bs8 am = *(const bs8*)(tA + aoff);
                bs8 an = *(const bs8*)(tB + aoff);
                accm[mt][0] = __builtin_amdgcn_mfma_f32_16x16x32_bf16(am, bf0, accm[mt][0], 0, 0, 0);
                accm[mt][1] = __builtin_amdgcn_mfma_f32_16x16x32_bf16(am, bf1, accm[mt][1], 0, 0, 0);
                accn[mt][0] = __builtin_amdgcn_mfma_f32_16x16x32_bf16(an, bf0, accn[mt][0], 0, 0, 0);
                accn[mt][1] = __builtin_amdgcn_mfma_f32_16x16x32_bf16(an, bf1, accn[mt][1], 0, 0, 0);
            }
        }
    }
    __syncthreads();   // UNION: all reads of hd/hs done before l1m/l1n writes

    #pragma unroll
    for (int nt = 0; nt < 2; nt++) {
        #pragma unroll
        for (int reg = 0; reg < 4; reg++) {
            int cg = (wid * 2 + nt) * 16 + cl4[reg];
            float bv = b1[cg];
            #pragma unroll
            for (int mt = 0; mt < 2; mt++) {
                int row = mt * 16 + rl4[reg];
                l1m[row][cg] = fmaxf(accm[mt][nt][reg] + bv, 0.f);
                l1n[row][cg] = fmaxf(accn[mt][nt][reg] + bv, 0.f);
            }
        }
    }
    __syncthreads();

    // ---- MFMA layer 2: A = cvt8(fp32 l1), B = w2p (KS=4) ----
    fx4 a2m[2][2], a2n[2][2];
    #pragma unroll
    for (int mt = 0; mt < 2; mt++)
        #pragma unroll
        for (int nt = 0; nt < 2; nt++) { fx4 z = {0.f, 0.f, 0.f, 0.f}; a2m[mt][nt] = z; a2n[mt][nt] = z; }

    #pragma unroll
    for (int kc = 0; kc < 4; kc++) {
        bs8 bf0 = *(const bs8*)(w2p + (((size_t)(wid * 2 + 0) * 4 + kc) * 64 + lane) * 8);
        bs8 bf1 = *(const bs8*)(w2p + (((size_t)(wid * 2 + 1) * 4 + kc) * 64 + lane) * 8);
        #pragma unroll
        for (int mt = 0; mt < 2; mt++) {
            int row = mt * 16 + r15;
            int k0 = kc * 32 + q * 8;
            bs8 am = cvt8(&l1m[row][k0]);
            bs8 an = cvt8(&l1n[row][k0]);
            a2m[mt][0] = __builtin_amdgcn_mfma_f32_16x16x32_bf16(am, bf0, a2m[mt][0], 0, 0, 0);
            a2m[mt][1] = __builtin_amdgcn_mfma_f32_16x16x32_bf16(am, bf1, a2m[mt][1], 0, 0, 0);
            a2n[mt][0] = __builtin_amdgcn_mfma_f32_16x16x32_bf16(an, bf0, a2n[mt][0], 0, 0, 0);
            a2n[mt][1] = __builtin_amdgcn_mfma_f32_16x16x32_bf16(an, bf1, a2n[mt][1], 0, 0, 0);
        }
    }
    __syncthreads();

    #pragma unroll
    for (int nt = 0; nt < 2; nt++) {
        #pragma unroll
        for (int reg = 0; reg < 4; reg++) {
            int cg = (wid * 2 + nt) * 16 + cl4[reg];
            float bv = b2[cg];
            #pragma unroll
            for (int mt = 0; mt < 2; mt++) {
                int row = mt * 16 + rl4[reg];
                l1m[row][cg] = fmaxf(a2m[mt][nt][reg] + bv, 0.f);
                l1n[row][cg] = fmaxf(a2n[mt][nt][reg] + bv, 0.f);
            }
        }
    }
    __syncthreads();

    // ---- LN epilogue (proven dual pattern), 8 rows per wave ----
    const float g0 = gam[lane], g1 = gam[lane + 64];
    const float be0 = bet[lane], be1 = bet[lane + 64];
    #pragma unroll
    for (int which = 0; which < 8; which++) {
        int row = wid * 8 + which;
        int ge = base + row;
        float v0 = l1m[row][lane], v1 = l1m[row][lane + 64];
        float u0 = l1n[row][lane], u1 = l1n[row][lane + 64];
        float s1m = v0 + v1, sqm = v0 * v0 + v1 * v1;
        float s1n = u0 + u1, sqn = u0 * u0 + u1 * u1;
        #pragma unroll
        for (int m = 32; m >= 1; m >>= 1) {
            s1m += __shfl_xor(s1m, m); sqm += __shfl_xor(sqm, m);
            s1n += __shfl_xor(s1n, m); sqn += __shfl_xor(sqn, m);
        }
        float mum = s1m * (1.f / LAT), varm = sqm * (1.f / LAT) - mum * mum;
        float mun = s1n * (1.f / LAT), varn = sqn * (1.f / LAT) - mun * mun;
        float im = rsqrtf(varm + EPS), in_ = rsqrtf(varn + EPS);
        if (ge < E) {
            int dn = sd[row];
            atomicAdd(&agg[(size_t)dn * LAT + lane],      (v0 - mum) * im * g0 + be0);
            atomicAdd(&agg[(size_t)dn * LAT + lane + 64], (v1 - mum) * im * g1 + be1);
            float e0 = bf2f(e_buf[(size_t)ge * LAT + lane]);
            float e1 = bf2f(e_buf[(size_t)ge * LAT + lane + 64]);
            e_buf[(size_t)ge * LAT + lane]      = f2bf((u0 - mun) * in_ * g0 + be0 + e0);
            e_buf[(size_t)ge * LAT + lane + 64] = f2bf((u1 - mun) * in_ * g1 + be1 + e1);
        }
    }
}

// ---------------------------------------------------------------------------
// Node step (r13 validated): MFMA L1 + MFMA L2 (cvt8), single fp32 LDS buffer.
// ---------------------------------------------------------------------------
__global__ __launch_bounds__(256, 4) void node_step_hybrid(
    float* __restrict__ agg, const unsigned short* __restrict__ h,
    unsigned short* __restrict__ h_out,
    const unsigned short* __restrict__ w1p, const unsigned short* __restrict__ w2p,
    const float* __restrict__ b1, const float* __restrict__ b2,
    const float* __restrict__ gam, const float* __restrict__ bet,
    const int* __restrict__ rowtab, const int* __restrict__ coltab, int N)
{
    __shared__ __align__(16) unsigned short aT[EB * TS];
    __shared__ __align__(16) unsigned short hT[EB * TS];
    __shared__ float l1f[EB][LATP];

    const int t = threadIdx.x;
    const int base = blockIdx.x * EB;

    for (int idx = t; idx < EB * 16; idx += 256) {
        int r = idx >> 4, c = idx & 15;
        int n = base + r;
        if (n < N) {
            float* ap = agg + (size_t)n * LAT + c * 8;
            float4 f0 = *(float4*)ap;
            float4 f1 = *(float4*)(ap + 4);
            float av[8] = {f0.x, f0.y, f0.z, f0.w, f1.x, f1.y, f1.z, f1.w};
            *(uint4*)&aT[r * TS + c * 8] = pack8(av);
            *(float4*)ap = make_float4(0.f, 0.f, 0.f, 0.f);
            *(float4*)(ap + 4) = make_float4(0.f, 0.f, 0.f, 0.f);
            *(uint4*)&hT[r * TS + c * 8] = *(const uint4*)(h + (size_t)n * LAT + c * 8);
        } else {
            uint4 z = make_uint4(0, 0, 0, 0);
            *(uint4*)&aT[r * TS + c * 8] = z;
            *(uint4*)&hT[r * TS + c * 8] = z;
        }
    }
    __syncthreads();

    const int wid = t >> 6, lane = t & 63;
    const int r15 = lane & 15, q = lane >> 4;

    int4 rt = *(const int4*)(rowtab + lane * 4);
    int4 ct = *(const int4*)(coltab + lane * 4);
    int rl4[4] = {rt.x, rt.y, rt.z, rt.w};
    int cl4[4] = {ct.x, ct.y, ct.z, ct.w};

    fx4 acc[2][2];
    #pragma unroll
    for (int mt = 0; mt < 2; mt++)
        #pragma unroll
        for (int nt = 0; nt < 2; nt++) { fx4 z = {0.f, 0.f, 0.f, 0.f}; acc[mt][nt] = z; }

    #pragma unroll
    for (int ts = 0; ts < 2; ts++) {
        const unsigned short* tA = ts ? hT : aT;
        #pragma unroll
        for (int kc = 0; kc < 4; kc++) {
            int ks = ts * 4 + kc;
            bs8 bf0 = *(const bs8*)(w1p + (((size_t)(wid * 2 + 0) * 8 + ks) * 64 + lane) * 8);
            bs8 bf1 = *(const bs8*)(w1p + (((size_t)(wid * 2 + 1) * 8 + ks) * 64 + lane) * 8);
            #pragma unroll
            for (int mt = 0; mt < 2; mt++) {
                bs8 a = *(const bs8*)(tA + (mt * 16 + r15) * TS + kc * 32 + q * 8);
                acc[mt][0] = __builtin_amdgcn_mfma_f32_16x16x32_bf16(a, bf0, acc[mt][0], 0, 0, 0);
                acc[mt][1] = __builtin_amdgcn_mfma_f32_16x16x32_bf16(a, bf1, acc[mt][1], 0, 0, 0);
            }
        }
    }
    #pragma unroll
    for (int nt = 0; nt < 2; nt++) {
        #pragma unroll
        for (int reg = 0; reg < 4; reg++) {
            int cg = (wid * 2 + nt) * 16 + cl4[reg];
            float bv = b1[cg];
            #pragma unroll
            for (int mt = 0; mt < 2; mt++) {
                int row = mt * 16 + rl4[reg];
                l1f[row][cg] = fmaxf(acc[mt][nt][reg] + bv, 0.f);
            }
        }
    }
    __syncthreads();

    fx4 a2[2][2];
    #pragma unroll
    for (int mt = 0; mt < 2; mt++)
        #pragma unroll
        for (int nt = 0; nt < 2; nt++) { fx4 z = {0.f, 0.f, 0.f, 0.f}; a2[mt][nt] = z; }

    #pragma unroll
    for (int kc = 0; kc < 4; kc++) {
        bs8 bf0 = *(const bs8*)(w2p + (((size_t)(wid * 2 + 0) * 4 + kc) * 64 + lane) * 8);
        bs8 bf1 = *(const bs8*)(w2p + (((size_t)(wid * 2 + 1) * 4 + kc) * 64 + lane) * 8);
        #pragma unroll
        for (int mt = 0; mt < 2; mt++) {
            int row = mt * 16 + r15;
            int k0 = kc * 32 + q * 8;
            bs8 a = cvt8(&l1f[row][k0]);
            a2[mt][0] = __builtin_amdgcn_mfma_f32_16x16x32_bf16(a, bf0, a2[mt][0], 0, 0, 0);
            a2[mt][1] = __builtin_amdgcn_mfma_f32_16x16x32_bf16(a, bf1, a2[mt][1], 0, 0, 0);
        }
    }
    __syncthreads();

    #pragma unroll
    for (int nt = 0; nt < 2; nt++) {
        #pragma unroll
        for (int reg = 0; reg < 4; reg++) {
            int cg = (wid * 2 + nt) * 16 + cl4[reg];
            float bv = b2[cg];
            #pragma unroll
            for (int mt = 0; mt < 2; mt++) {
                int row = mt * 16 + rl4[reg];
                l1f[row][cg] = fmaxf(a2[mt][nt][reg] + bv, 0.f);
            }
        }
    }
    __syncthreads();

    const float g0 = gam[lane], g1 = gam[lane + 64];
    const float be0 = bet[lane], be1 = bet[lane + 64];
    #pragma unroll
    for (int which = 0; which < 8; which++) {
        int row = wid * 8 + which;
        int n = base + row;
        float v0 = l1f[row][lane], v1 = l1f[row][lane + 64];
        float s1 = v0 + v1, sq = v0 * v0 + v1 * v1;
        #pragma unroll
        for (int m = 32; m >= 1; m >>= 1) { s1 += __shfl_xor(s1, m); sq += __shfl_xor(sq, m); }
        float mu = s1 * (1.f / LAT);
        float var = sq * (1.f / LAT) - mu * mu;
        float inv = rsqrtf(var + EPS);
        if (n < N) {
            float h0 = bf2f(hT[row * TS + lane]);
            float h1 = bf2f(hT[row * TS + lane + 64]);
            h_out[(size_t)n * LAT + lane]      = f2bf((v0 - mu) * inv * g0 + be0 + h0);
            h_out[(size_t)n * LAT + lane + 64] = f2bf((v1 - mu) * inv * g1 + be1 + h1);
        }
    }
}

// ---------------------------------------------------------------------------
// Decoder (PROVEN)
// ---------------------------------------------------------------------------
__global__ __launch_bounds__(256) void decode_kernel(
    const unsigned short* __restrict__ h, float* __restrict__ out,
    const float* __restrict__ w1, const float* __restrict__ b1,
    const float* __restrict__ w2, const float* __restrict__ b2, int N)
{
    __shared__ float hv[8][LAT], d1[8][LAT];
    const int t = threadIdx.x;
    const int base = blockIdx.x * 8;
    for (int idx = t; idx < 8 * 16; idx += 256) {
        int e = idx >> 4; int c8 = (idx & 15) * 8;
        int n = base + e;
        float v[8];
        for (int u = 0; u < 8; u++) v[u] = 0.f;
        if (n < N) unpack8(*(const uint4*)(h + (size_t)n * LAT + c8), v);
        for (int u = 0; u < 8; u++) hv[e][c8 + u] = v[u];
    }
    __syncthreads();
    const int j = t & 127, g = t >> 7;
    float s[4] = {0, 0, 0, 0};
    for (int k = 0; k < LAT; k += 4) {
        float w[4];
        #pragma unroll
        for (int u = 0; u < 4; u++) w[u] = w1[(k + u) * LAT + j];
        #pragma unroll
        for (int i = 0; i < 4; i++) {
            int e = g + 2 * i;
            float4 v4 = *(const float4*)&hv[e][k];
            s[i] += v4.x * w[0] + v4.y * w[1] + v4.z * w[2] + v4.w * w[3];
        }
    }
    const float bb = b1[j];
    #pragma unroll
    for (int i = 0; i < 4; i++) { int e = g + 2 * i; d1[e][j] = fmaxf(s[i] + bb, 0.f); }
    __syncthreads();
    const int wv_ = t >> 6, lane = t & 63;
    #pragma unroll
    for (int which = 0; which < 2; which++) {
        int e = 2 * wv_ + which; int n = base + e;
        if (n >= N) continue;
        float a0 = 0.f, a1 = 0.f, a2 = 0.f;
        #pragma unroll
        for (int kk = 0; kk < 2; kk++) {
            int k = lane + 64 * kk;
            float v = d1[e][k];
            a0 += v * w2[k * 3 + 0];
            a1 += v * w2[k * 3 + 1];
            a2 += v * w2[k * 3 + 2];
        }
        #pragma unroll
        for (int m = 32; m >= 1; m >>= 1) {
            a0 += __shfl_xor(a0, m); a1 += __shfl_xor(a1, m); a2 += __shfl_xor(a2, m);
        }
        if (lane == 0) {
            out[(size_t)n * 3 + 0] = a0 + b2[0];
            out[(size_t)n * 3 + 1] = a1 + b2[1];
            out[(size_t)n * 3 + 2] = a2 + b2[2];
        }
    }
}

extern "C" void kernel_launch(void* const* d_in, const int* in_sizes, int n_in,
                              void* d_out, int out_size, void* d_ws, size_t ws_size,
                              hipStream_t stream) {
    const float* x         = (const float*)d_in[0];
    const float* edge_attr = (const float*)d_in[1];
    const int*   ei        = (const int*)d_in[2];
    const float* ne_w1 = (const float*)d_in[3];  const float* ne_b1 = (const float*)d_in[4];
    const float* ne_w2 = (const float*)d_in[5];  const float* ne_b2 = (const float*)d_in[6];
    const float* ne_g  = (const float*)d_in[7];  const float* ne_be = (const float*)d_in[8];
    const float* ee_w1 = (const float*)d_in[9];  const float* ee_b1 = (const float*)d_in[10];
    const float* ee_w2 = (const float*)d_in[11]; const float* ee_b2 = (const float*)d_in[12];
    const float* ee_g  = (const float*)d_in[13]; const float* ee_be = (const float*)d_in[14];
    const float* em_w1 = (const float*)d_in[15]; const float* em_b1 = (const float*)d_in[16];
    const float* em_w2 = (const float*)d_in[17]; const float* em_b2 = (const float*)d_in[18];
    const float* em_g  = (const float*)d_in[19]; const float* em_be = (const float*)d_in[20];
    const float* nm_w1 = (const float*)d_in[21]; const float* nm_b1 = (const float*)d_in[22];
    const float* nm_w2 = (const float*)d_in[23]; const float* nm_b2 = (const float*)d_in[24];
    const float* nm_g  = (const float*)d_in[25]; const float* nm_be = (const float*)d_in[26];
    const float* dec_w1 = (const float*)d_in[27]; const float* dec_b1 = (const float*)d_in[28];
    const float* dec_w2 = (const float*)d_in[29]; const float* dec_b2 = (const float*)d_in[30];

    const int N = in_sizes[0] / 3;
    const int E = in_sizes[2] / 2;

    unsigned short* hA   = (unsigned short*)d_ws;
    unsigned short* hB   = hA + (size_t)N * LAT;
    unsigned short* ebuf = hB + (size_t)N * LAT;
    float*          agg  = (float*)(ebuf + (size_t)E * LAT);
    unsigned short* ew1p = (unsigned short*)(agg + (size_t)N * LAT);
    unsigned short* ew2p = ew1p + 12 * 4096;
    unsigned short* nw1p = ew2p + 4 * 4096;
    unsigned short* nw2p = nw1p + 8 * 4096;
    unsigned short* neW2p = nw2p + 4 * 4096;
    unsigned short* eeW2p = neW2p + 4 * 4096;
    int*            rowtab = (int*)(eeW2p + 4 * 4096);
    int*            coltab = rowtab + 256;

    const dim3 blk(256);

    probe_kernel<<<1, 64, 0, stream>>>(rowtab, coltab);
    pack_w_kernel<<<(12 * 4096 + 255) / 256, blk, 0, stream>>>(em_w1, ew1p, 12);
    pack_w_kernel<<<(4  * 4096 + 255) / 256, blk, 0, stream>>>(em_w2, ew2p, 4);
    pack_w_kernel<<<(8  * 4096 + 255) / 256, blk, 0, stream>>>(nm_w1, nw1p, 8);
    pack_w_kernel<<<(4  * 4096 + 255) / 256, blk, 0, stream>>>(nm_w2, nw2p, 4);
    pack_w_kernel<<<(4  * 4096 + 255) / 256, blk, 0, stream>>>(ne_w2, neW2p, 4);
    pack_w_kernel<<<(4  * 4096 + 255) / 256, blk, 0, stream>>>(ee_w2, eeW2p, 4);

    const int n4 = (N * LAT) / 4;
    zero_kernel<<<(n4 + 255) / 256, blk, 0, stream>>>((float4*)agg, n4);

    const int nb_n32 = (N + EB - 1) / EB;
    const int nb_e32 = (E + EB - 1) / EB;
    encode_hybrid<3><<<nb_n32, blk, 0, stream>>>(x, hA, ne_w1, ne_b1, neW2p, ne_b2,
                                                 ne_g, ne_be, rowtab, coltab, N);
    encode_hybrid<4><<<nb_e32, blk, 0, stream>>>(edge_attr, ebuf, ee_w1, ee_b1, eeW2p, ee_b2,
                                                 ee_g, ee_be, rowtab, coltab, E);

    unsigned short* hc = hA; unsigned short* hn = hB;
    for (int s = 0; s < 5; s++) {
        edge_step_hybrid<<<nb_e32, blk, 0, stream>>>(hc, ebuf, agg, ei,
                                                     ew1p, ew2p, em_b1, em_b2, em_g, em_be,
                                                     rowtab, coltab, E);
        node_step_hybrid<<<nb_n32, blk, 0, stream>>>(agg, hc, hn,
                                                     nw1p, nw2p, nm_b1, nm_b2, nm_g, nm_be,
                                                     rowtab, coltab, N);
        unsigned short* tmp = hc; hc = hn; hn = tmp;
    }
    const int nb_n8 = (N + 7) / 8;
    decode_kernel<<<nb_n8, blk, 0, stream>>>(hc, (float*)d_out, dec_w1, dec_b1, dec_w2, dec_b2, N);
}

// Round 17
// 1633.211 us; speedup vs baseline: 1.0755x; 1.0755x over previous
//
#include <hip/hip_runtime.h>

#define LAT 128
#define LATP 132   // padded fp32 LDS row stride -> reduced-conflict MFMA A-reads
#define EPS 1e-5f
#define EB 32
#define TS 136     // bf16 tile row stride in shorts

typedef __attribute__((ext_vector_type(8))) short bs8;
typedef __attribute__((ext_vector_type(4))) float fx4;

__device__ __forceinline__ float bf2f(unsigned int u) {
    return __uint_as_float(u << 16);
}
__device__ __forceinline__ unsigned short f2bf(float f) {
    unsigned int x = __float_as_uint(f);
    x += 0x7fffu + ((x >> 16) & 1u);   // round-to-nearest-even
    return (unsigned short)(x >> 16);
}
__device__ __forceinline__ void unpack8(uint4 u, float* v) {
    v[0] = bf2f(u.x & 0xffffu); v[1] = bf2f(u.x >> 16);
    v[2] = bf2f(u.y & 0xffffu); v[3] = bf2f(u.y >> 16);
    v[4] = bf2f(u.z & 0xffffu); v[5] = bf2f(u.z >> 16);
    v[6] = bf2f(u.w & 0xffffu); v[7] = bf2f(u.w >> 16);
}
__device__ __forceinline__ uint4 pack8(const float* v) {
    uint4 u;
    u.x = (unsigned)f2bf(v[0]) | ((unsigned)f2bf(v[1]) << 16);
    u.y = (unsigned)f2bf(v[2]) | ((unsigned)f2bf(v[3]) << 16);
    u.z = (unsigned)f2bf(v[4]) | ((unsigned)f2bf(v[5]) << 16);
    u.w = (unsigned)f2bf(v[6]) | ((unsigned)f2bf(v[7]) << 16);
    return u;
}
// fp32 LDS -> bf16 A-fragment (8 consecutive features)
__device__ __forceinline__ bs8 cvt8(const float* p) {
    bs8 r;
    #pragma unroll
    for (int i = 0; i < 8; i++) r[i] = (short)f2bf(p[i]);
    return r;
}

__global__ __launch_bounds__(256) void zero_kernel(float4* __restrict__ p, int n4) {
    int i = blockIdx.x * 256 + threadIdx.x;
    if (i < n4) p[i] = make_float4(0.f, 0.f, 0.f, 0.f);
}

// ---------------------------------------------------------------------------
// C/D-map probe (pi-invariant), VALIDATED round 8.
// ---------------------------------------------------------------------------
__global__ void probe_kernel(int* __restrict__ rowtab, int* __restrict__ coltab) {
    int l = threadIdx.x;
    bs8 idv, ones;
    unsigned short ridb = f2bf((float)(l & 15));
    unsigned short oneb = f2bf(1.f);
    #pragma unroll
    for (int i = 0; i < 8; i++) { idv[i] = (short)ridb; ones[i] = (short)oneb; }
    fx4 dR = {0.f, 0.f, 0.f, 0.f};
    fx4 dC = {0.f, 0.f, 0.f, 0.f};
    dR = __builtin_amdgcn_mfma_f32_16x16x32_bf16(idv, ones, dR, 0, 0, 0);
    dC = __builtin_amdgcn_mfma_f32_16x16x32_bf16(ones, idv, dC, 0, 0, 0);
    #pragma unroll
    for (int reg = 0; reg < 4; reg++) {
        rowtab[l * 4 + reg] = ((int)(dR[reg] * (1.f / 32.f) + 0.5f)) & 15;
        coltab[l * 4 + reg] = ((int)(dC[reg] * (1.f / 32.f) + 0.5f)) & 15;
    }
}

// Pack fp32 weight [K=KS*32][128] into MFMA B-fragment order, bf16. VALIDATED r8.
__global__ __launch_bounds__(256) void pack_w_kernel(
    const float* __restrict__ src, unsigned short* __restrict__ dst, int KS)
{
    int id = blockIdx.x * 256 + threadIdx.x;
    if (id >= KS * 4096) return;
    int j = id & 7;
    int l = (id >> 3) & 63;
    int rest = id >> 9;
    int ks = rest % KS, nt = rest / KS;
    int k = ks * 32 + (l >> 4) * 8 + j;
    int n = nt * 16 + (l & 15);
    dst[id] = f2bf(src[k * 128 + n]);
}

// ---------------------------------------------------------------------------
// HYBRID encoder (r13 validated): VALU L1 -> fp32 LDS -> MFMA L2 -> LN.
// ---------------------------------------------------------------------------
template<int KIN>
__global__ __launch_bounds__(256, 4) void encode_hybrid(
    const float* __restrict__ x, unsigned short* __restrict__ out,
    const float* __restrict__ w1, const float* __restrict__ b1,
    const unsigned short* __restrict__ w2p, const float* __restrict__ b2,
    const float* __restrict__ gam, const float* __restrict__ bet,
    const int* __restrict__ rowtab, const int* __restrict__ coltab, int M)
{
    __shared__ float l1f[EB][LATP];

    const int t = threadIdx.x;
    const int base = blockIdx.x * EB;
    const int j = t & 127, g = t >> 7;

    float wv[KIN];
    #pragma unroll
    for (int u = 0; u < KIN; u++) wv[u] = w1[u * LAT + j];
    const float bb = b1[j];
    #pragma unroll
    for (int i = 0; i < 16; i++) {
        int r = g + 2 * i; int row = base + r;
        float acc = bb;
        if (row < M) {
            #pragma unroll
            for (int u = 0; u < KIN; u++) acc += x[(size_t)row * KIN + u] * wv[u];
        }
        l1f[r][j] = fmaxf(acc, 0.f);
    }
    __syncthreads();

    const int wid = t >> 6, lane = t & 63;
    const int r15 = lane & 15, q = lane >> 4;

    int4 rt = *(const int4*)(rowtab + lane * 4);
    int4 ct = *(const int4*)(coltab + lane * 4);
    int rl4[4] = {rt.x, rt.y, rt.z, rt.w};
    int cl4[4] = {ct.x, ct.y, ct.z, ct.w};

    fx4 a2[2][2];
    #pragma unroll
    for (int mt = 0; mt < 2; mt++)
        #pragma unroll
        for (int nt = 0; nt < 2; nt++) { fx4 z = {0.f, 0.f, 0.f, 0.f}; a2[mt][nt] = z; }

    #pragma unroll
    for (int kc = 0; kc < 4; kc++) {
        bs8 bf0 = *(const bs8*)(w2p + (((size_t)(wid * 2 + 0) * 4 + kc) * 64 + lane) * 8);
        bs8 bf1 = *(const bs8*)(w2p + (((size_t)(wid * 2 + 1) * 4 + kc) * 64 + lane) * 8);
        #pragma unroll
        for (int mt = 0; mt < 2; mt++) {
            int row = mt * 16 + r15;
            int k0 = kc * 32 + q * 8;
            bs8 a = cvt8(&l1f[row][k0]);
            a2[mt][0] = __builtin_amdgcn_mfma_f32_16x16x32_bf16(a, bf0, a2[mt][0], 0, 0, 0);
            a2[mt][1] = __builtin_amdgcn_mfma_f32_16x16x32_bf16(a, bf1, a2[mt][1], 0, 0, 0);
        }
    }
    __syncthreads();

    #pragma unroll
    for (int nt = 0; nt < 2; nt++) {
        #pragma unroll
        for (int reg = 0; reg < 4; reg++) {
            int cg = (wid * 2 + nt) * 16 + cl4[reg];
            float bv = b2[cg];
            #pragma unroll
            for (int mt = 0; mt < 2; mt++) {
                int row = mt * 16 + rl4[reg];
                l1f[row][cg] = fmaxf(a2[mt][nt][reg] + bv, 0.f);
            }
        }
    }
    __syncthreads();

    const float g0 = gam[lane], g1 = gam[lane + 64];
    const float be0 = bet[lane], be1 = bet[lane + 64];
    #pragma unroll
    for (int which = 0; which < 8; which++) {
        int row = wid * 8 + which;
        int rowg = base + row;
        float v0 = l1f[row][lane], v1 = l1f[row][lane + 64];
        float s1 = v0 + v1, sq = v0 * v0 + v1 * v1;
        #pragma unroll
        for (int m = 32; m >= 1; m >>= 1) { s1 += __shfl_xor(s1, m); sq += __shfl_xor(sq, m); }
        float mu = s1 * (1.f / LAT);
        float var = sq * (1.f / LAT) - mu * mu;
        float inv = rsqrtf(var + EPS);
        if (rowg < M) {
            out[(size_t)rowg * LAT + lane]      = f2bf((v0 - mu) * inv * g0 + be0);
            out[(size_t)rowg * LAT + lane + 64] = f2bf((v1 - mu) * inv * g1 + be1);
        }
    }
}

// ---------------------------------------------------------------------------
// Edge step (r13 validated): LDS union (hd/hs -> l1m/l1n) -> 34KB -> 4 blk/CU.
// ev direct from global. MFMA L1 dual + MFMA L2 (cvt8).
// ---------------------------------------------------------------------------
__global__ __launch_bounds__(256, 4) void edge_step_hybrid(
    const unsigned short* __restrict__ h, unsigned short* __restrict__ e_buf,
    float* __restrict__ agg, const int* __restrict__ ei,
    const unsigned short* __restrict__ w1p, const unsigned short* __restrict__ w2p,
    const float* __restrict__ b1, const float* __restrict__ b2,
    const float* __restrict__ gam, const float* __restrict__ bet,
    const int* __restrict__ rowtab, const int* __restrict__ coltab, int E)
{
    __shared__ __align__(16) float poolf[2 * EB * LATP];   // 33.8KB union
    __shared__ int sd[EB], ss[EB];
    unsigned short* hd = (unsigned short*)poolf;
    unsigned short* hs = (unsigned short*)poolf + EB * TS;
    float (*l1m)[LATP] = (float(*)[LATP])poolf;
    float (*l1n)[LATP] = (float(*)[LATP])(poolf + EB * LATP);

    const int t = threadIdx.x;
    const int base = blockIdx.x * EB;
    if (t < EB) {
        int ge = base + t;
        sd[t] = (ge < E) ? ei[E + ge] : 0;  // dst
        ss[t] = (ge < E) ? ei[ge] : 0;      // src
    }
    __syncthreads();

    for (int idx = t; idx < 2 * EB * 16; idx += 256) {
        int seg = idx / (EB * 16);
        int rem = idx - seg * (EB * 16);
        int r = rem >> 4, c = rem & 15;
        int ge = base + r;
        uint4 v = make_uint4(0, 0, 0, 0);
        if (ge < E) {
            const unsigned short* src = h + (size_t)(seg == 0 ? sd[r] : ss[r]) * LAT;
            v = *(const uint4*)(src + c * 8);
        }
        unsigned short* dstT = (seg == 0) ? hd : hs;
        *(uint4*)&dstT[r * TS + c * 8] = v;
    }
    __syncthreads();

    const int wid = t >> 6, lane = t & 63;
    const int r15 = lane & 15, q = lane >> 4;

    int4 rt = *(const int4*)(rowtab + lane * 4);
    int4 ct = *(const int4*)(coltab + lane * 4);
    int rl4[4] = {rt.x, rt.y, rt.z, rt.w};
    int cl4[4] = {ct.x, ct.y, ct.z, ct.w};

    // ---- MFMA layer 1, dual accumulators, shared ev@WB (ev from global) ----
    fx4 accm[2][2], accn[2][2];
    #pragma unroll
    for (int mt = 0; mt < 2; mt++)
        #pragma unroll
        for (int nt = 0; nt < 2; nt++) { fx4 z = {0.f, 0.f, 0.f, 0.f}; accm[mt][nt] = z; }

    #pragma unroll
    for (int kc = 0; kc < 4; kc++) {
        int ks = 8 + kc;
        bs8 bf0 = *(const bs8*)(w1p + (((size_t)(wid * 2 + 0) * 12 + ks) * 64 + lane) * 8);
        bs8 bf1 = *(const bs8*)(w1p + (((size_t)(wid * 2 + 1) * 12 + ks) * 64 + lane) * 8);
        #pragma unroll
        for (int mt = 0; mt < 2; mt++) {
            bs8 ae = *(const bs8*)(e_buf + (size_t)(base + mt * 16 + r15) * LAT + kc * 32 + q * 8);
            accm[mt][0] = __builtin_amdgcn_mfma_f32_16x16x32_bf16(ae, bf0, accm[mt][0], 0, 0, 0);
            accm[mt][1] = __builtin_amdgcn_mfma_f32_16x16x32_bf16(ae, bf1, accm[mt][1], 0, 0, 0);
        }
    }
    #pragma unroll
    for (int mt = 0; mt < 2; mt++) { accn[mt][0] = accm[mt][0]; accn[mt][1] = accm[mt][1]; }

    #pragma unroll
    for (int ts = 0; ts < 2; ts++) {
        const unsigned short* tA = ts ? hs : hd;
        const unsigned short* tB = ts ? hd : hs;
        #pragma unroll
        for (int kc = 0; kc < 4; kc++) {
            int ks = ts * 4 + kc;
            bs8 bf0 = *(const bs8*)(w1p + (((size_t)(wid * 2 + 0) * 12 + ks) * 64 + lane) * 8);
            bs8 bf1 = *(const bs8*)(w1p + (((size_t)(wid * 2 + 1) * 12 + ks) * 64 + lane) * 8);
            #pragma unroll
            for (int mt = 0; mt < 2; mt++) {
                int aoff = (mt * 16 + r15) * TS + kc * 32 + q * 8;
                bs8 am = *(const bs8*)(tA + aoff);
                bs8 an = *(const bs8*)(tB + aoff);
                accm[mt][0] = __builtin_amdgcn_mfma_f32_16x16x32_bf16(am, bf0, accm[mt][0], 0, 0, 0);
                accm[mt][1] = __builtin_amdgcn_mfma_f32_16x16x32_bf16(am, bf1, accm[mt][1], 0, 0, 0);
                accn[mt][0] = __builtin_amdgcn_mfma_f32_16x16x32_bf16(an, bf0, accn[mt][0], 0, 0, 0);
                accn[mt][1] = __builtin_amdgcn_mfma_f32_16x16x32_bf16(an, bf1, accn[mt][1], 0, 0, 0);
            }
        }
    }
    __syncthreads();   // UNION: all reads of hd/hs done before l1m/l1n writes

    #pragma unroll
    for (int nt = 0; nt < 2; nt++) {
        #pragma unroll
        for (int reg = 0; reg < 4; reg++) {
            int cg = (wid * 2 + nt) * 16 + cl4[reg];
            float bv = b1[cg];
            #pragma unroll
            for (int mt = 0; mt < 2; mt++) {
                int row = mt * 16 + rl4[reg];
                l1m[row][cg] = fmaxf(accm[mt][nt][reg] + bv, 0.f);
                l1n[row][cg] = fmaxf(accn[mt][nt][reg] + bv, 0.f);
            }
        }
    }
    __syncthreads();

    // ---- MFMA layer 2: A = cvt8(fp32 l1), B = w2p (KS=4) ----
    fx4 a2m[2][2], a2n[2][2];
    #pragma unroll
    for (int mt = 0; mt < 2; mt++)
        #pragma unroll
        for (int nt = 0; nt < 2; nt++) { fx4 z = {0.f, 0.f, 0.f, 0.f}; a2m[mt][nt] = z; a2n[mt][nt] = z; }

    #pragma unroll
    for (int kc = 0; kc < 4; kc++) {
        bs8 bf0 = *(const bs8*)(w2p + (((size_t)(wid * 2 + 0) * 4 + kc) * 64 + lane) * 8);
        bs8 bf1 = *(const bs8*)(w2p + (((size_t)(wid * 2 + 1) * 4 + kc) * 64 + lane) * 8);
        #pragma unroll
        for (int mt = 0; mt < 2; mt++) {
            int row = mt * 16 + r15;
            int k0 = kc * 32 + q * 8;
            bs8 am = cvt8(&l1m[row][k0]);
            bs8 an = cvt8(&l1n[row][k0]);
            a2m[mt][0] = __builtin_amdgcn_mfma_f32_16x16x32_bf16(am, bf0, a2m[mt][0], 0, 0, 0);
            a2m[mt][1] = __builtin_amdgcn_mfma_f32_16x16x32_bf16(am, bf1, a2m[mt][1], 0, 0, 0);
            a2n[mt][0] = __builtin_amdgcn_mfma_f32_16x16x32_bf16(an, bf0, a2n[mt][0], 0, 0, 0);
            a2n[mt][1] = __builtin_amdgcn_mfma_f32_16x16x32_bf16(an, bf1, a2n[mt][1], 0, 0, 0);
        }
    }
    __syncthreads();

    #pragma unroll
    for (int nt = 0; nt < 2; nt++) {
        #pragma unroll
        for (int reg = 0; reg < 4; reg++) {
            int cg = (wid * 2 + nt) * 16 + cl4[reg];
            float bv = b2[cg];
            #pragma unroll
            for (int mt = 0; mt < 2; mt++) {
                int row = mt * 16 + rl4[reg];
                l1m[row][cg] = fmaxf(a2m[mt][nt][reg] + bv, 0.f);
                l1n[row][cg] = fmaxf(a2n[mt][nt][reg] + bv, 0.f);
            }
        }
    }
    __syncthreads();

    // ---- LN epilogue (proven dual pattern), 8 rows per wave ----
    const float g0 = gam[lane], g1 = gam[lane + 64];
    const float be0 = bet[lane], be1 = bet[lane + 64];
    #pragma unroll
    for (int which = 0; which < 8; which++) {
        int row = wid * 8 + which;
        int ge = base + row;
        float v0 = l1m[row][lane], v1 = l1m[row][lane + 64];
        float u0 = l1n[row][lane], u1 = l1n[row][lane + 64];
        float s1m = v0 + v1, sqm = v0 * v0 + v1 * v1;
        float s1n = u0 + u1, sqn = u0 * u0 + u1 * u1;
        #pragma unroll
        for (int m = 32; m >= 1; m >>= 1) {
            s1m += __shfl_xor(s1m, m); sqm += __shfl_xor(sqm, m);
            s1n += __shfl_xor(s1n, m); sqn += __shfl_xor(sqn, m);
        }
        float mum = s1m * (1.f / LAT), varm = sqm * (1.f / LAT) - mum * mum;
        float mun = s1n * (1.f / LAT), varn = sqn * (1.f / LAT) - mun * mun;
        float im = rsqrtf(varm + EPS), in_ = rsqrtf(varn + EPS);
        if (ge < E) {
            int dn = sd[row];
            atomicAdd(&agg[(size_t)dn * LAT + lane],      (v0 - mum) * im * g0 + be0);
            atomicAdd(&agg[(size_t)dn * LAT + lane + 64], (v1 - mum) * im * g1 + be1);
            float e0 = bf2f(e_buf[(size_t)ge * LAT + lane]);
            float e1 = bf2f(e_buf[(size_t)ge * LAT + lane + 64]);
            e_buf[(size_t)ge * LAT + lane]      = f2bf((u0 - mun) * in_ * g0 + be0 + e0);
            e_buf[(size_t)ge * LAT + lane + 64] = f2bf((u1 - mun) * in_ * g1 + be1 + e1);
        }
    }
}

// ---------------------------------------------------------------------------
// Node step (r13 validated): MFMA L1 + MFMA L2 (cvt8), single fp32 LDS buffer.
// ---------------------------------------------------------------------------
__global__ __launch_bounds__(256, 4) void node_step_hybrid(
    float* __restrict__ agg, const unsigned short* __restrict__ h,
    unsigned short* __restrict__ h_out,
    const unsigned short* __restrict__ w1p, const unsigned short* __restrict__ w2p,
    const float* __restrict__ b1, const float* __restrict__ b2,
    const float* __restrict__ gam, const float* __restrict__ bet,
    const int* __restrict__ rowtab, const int* __restrict__ coltab, int N)
{
    __shared__ __align__(16) unsigned short aT[EB * TS];
    __shared__ __align__(16) unsigned short hT[EB * TS];
    __shared__ float l1f[EB][LATP];

    const int t = threadIdx.x;
    const int base = blockIdx.x * EB;

    for (int idx = t; idx < EB * 16; idx += 256) {
        int r = idx >> 4, c = idx & 15;
        int n = base + r;
        if (n < N) {
            float* ap = agg + (size_t)n * LAT + c * 8;
            float4 f0 = *(float4*)ap;
            float4 f1 = *(float4*)(ap + 4);
            float av[8] = {f0.x, f0.y, f0.z, f0.w, f1.x, f1.y, f1.z, f1.w};
            *(uint4*)&aT[r * TS + c * 8] = pack8(av);
            *(float4*)ap = make_float4(0.f, 0.f, 0.f, 0.f);
            *(float4*)(ap + 4) = make_float4(0.f, 0.f, 0.f, 0.f);
            *(uint4*)&hT[r * TS + c * 8] = *(const uint4*)(h + (size_t)n * LAT + c * 8);
        } else {
            uint4 z = make_uint4(0, 0, 0, 0);
            *(uint4*)&aT[r * TS + c * 8] = z;
            *(uint4*)&hT[r * TS + c * 8] = z;
        }
    }
    __syncthreads();

    const int wid = t >> 6, lane = t & 63;
    const int r15 = lane & 15, q = lane >> 4;

    int4 rt = *(const int4*)(rowtab + lane * 4);
    int4 ct = *(const int4*)(coltab + lane * 4);
    int rl4[4] = {rt.x, rt.y, rt.z, rt.w};
    int cl4[4] = {ct.x, ct.y, ct.z, ct.w};

    fx4 acc[2][2];
    #pragma unroll
    for (int mt = 0; mt < 2; mt++)
        #pragma unroll
        for (int nt = 0; nt < 2; nt++) { fx4 z = {0.f, 0.f, 0.f, 0.f}; acc[mt][nt] = z; }

    #pragma unroll
    for (int ts = 0; ts < 2; ts++) {
        const unsigned short* tA = ts ? hT : aT;
        #pragma unroll
        for (int kc = 0; kc < 4; kc++) {
            int ks = ts * 4 + kc;
            bs8 bf0 = *(const bs8*)(w1p + (((size_t)(wid * 2 + 0) * 8 + ks) * 64 + lane) * 8);
            bs8 bf1 = *(const bs8*)(w1p + (((size_t)(wid * 2 + 1) * 8 + ks) * 64 + lane) * 8);
            #pragma unroll
            for (int mt = 0; mt < 2; mt++) {
                bs8 a = *(const bs8*)(tA + (mt * 16 + r15) * TS + kc * 32 + q * 8);
                acc[mt][0] = __builtin_amdgcn_mfma_f32_16x16x32_bf16(a, bf0, acc[mt][0], 0, 0, 0);
                acc[mt][1] = __builtin_amdgcn_mfma_f32_16x16x32_bf16(a, bf1, acc[mt][1], 0, 0, 0);
            }
        }
    }
    #pragma unroll
    for (int nt = 0; nt < 2; nt++) {
        #pragma unroll
        for (int reg = 0; reg < 4; reg++) {
            int cg = (wid * 2 + nt) * 16 + cl4[reg];
            float bv = b1[cg];
            #pragma unroll
            for (int mt = 0; mt < 2; mt++) {
                int row = mt * 16 + rl4[reg];
                l1f[row][cg] = fmaxf(acc[mt][nt][reg] + bv, 0.f);
            }
        }
    }
    __syncthreads();

    fx4 a2[2][2];
    #pragma unroll
    for (int mt = 0; mt < 2; mt++)
        #pragma unroll
        for (int nt = 0; nt < 2; nt++) { fx4 z = {0.f, 0.f, 0.f, 0.f}; a2[mt][nt] = z; }

    #pragma unroll
    for (int kc = 0; kc < 4; kc++) {
        bs8 bf0 = *(const bs8*)(w2p + (((size_t)(wid * 2 + 0) * 4 + kc) * 64 + lane) * 8);
        bs8 bf1 = *(const bs8*)(w2p + (((size_t)(wid * 2 + 1) * 4 + kc) * 64 + lane) * 8);
        #pragma unroll
        for (int mt = 0; mt < 2; mt++) {
            int row = mt * 16 + r15;
            int k0 = kc * 32 + q * 8;
            bs8 a = cvt8(&l1f[row][k0]);
            a2[mt][0] = __builtin_amdgcn_mfma_f32_16x16x32_bf16(a, bf0, a2[mt][0], 0, 0, 0);
            a2[mt][1] = __builtin_amdgcn_mfma_f32_16x16x32_bf16(a, bf1, a2[mt][1], 0, 0, 0);
        }
    }
    __syncthreads();

    #pragma unroll
    for (int nt = 0; nt < 2; nt++) {
        #pragma unroll
        for (int reg = 0; reg < 4; reg++) {
            int cg = (wid * 2 + nt) * 16 + cl4[reg];
            float bv = b2[cg];
            #pragma unroll
            for (int mt = 0; mt < 2; mt++) {
                int row = mt * 16 + rl4[reg];
                l1f[row][cg] = fmaxf(a2[mt][nt][reg] + bv, 0.f);
            }
        }
    }
    __syncthreads();

    const float g0 = gam[lane], g1 = gam[lane + 64];
    const float be0 = bet[lane], be1 = bet[lane + 64];
    #pragma unroll
    for (int which = 0; which < 8; which++) {
        int row = wid * 8 + which;
        int n = base + row;
        float v0 = l1f[row][lane], v1 = l1f[row][lane + 64];
        float s1 = v0 + v1, sq = v0 * v0 + v1 * v1;
        #pragma unroll
        for (int m = 32; m >= 1; m >>= 1) { s1 += __shfl_xor(s1, m); sq += __shfl_xor(sq, m); }
        float mu = s1 * (1.f / LAT);
        float var = sq * (1.f / LAT) - mu * mu;
        float inv = rsqrtf(var + EPS);
        if (n < N) {
            float h0 = bf2f(hT[row * TS + lane]);
            float h1 = bf2f(hT[row * TS + lane + 64]);
            h_out[(size_t)n * LAT + lane]      = f2bf((v0 - mu) * inv * g0 + be0 + h0);
            h_out[(size_t)n * LAT + lane + 64] = f2bf((v1 - mu) * inv * g1 + be1 + h1);
        }
    }
}

// ---------------------------------------------------------------------------
// Decoder (PROVEN)
// ---------------------------------------------------------------------------
__global__ __launch_bounds__(256) void decode_kernel(
    const unsigned short* __restrict__ h, float* __restrict__ out,
    const float* __restrict__ w1, const float* __restrict__ b1,
    const float* __restrict__ w2, const float* __restrict__ b2, int N)
{
    __shared__ float hv[8][LAT], d1[8][LAT];
    const int t = threadIdx.x;
    const int base = blockIdx.x * 8;
    for (int idx = t; idx < 8 * 16; idx += 256) {
        int e = idx >> 4; int c8 = (idx & 15) * 8;
        int n = base + e;
        float v[8];
        for (int u = 0; u < 8; u++) v[u] = 0.f;
        if (n < N) unpack8(*(const uint4*)(h + (size_t)n * LAT + c8), v);
        for (int u = 0; u < 8; u++) hv[e][c8 + u] = v[u];
    }
    __syncthreads();
    const int j = t & 127, g = t >> 7;
    float s[4] = {0, 0, 0, 0};
    for (int k = 0; k < LAT; k += 4) {
        float w[4];
        #pragma unroll
        for (int u = 0; u < 4; u++) w[u] = w1[(k + u) * LAT + j];
        #pragma unroll
        for (int i = 0; i < 4; i++) {
            int e = g + 2 * i;
            float4 v4 = *(const float4*)&hv[e][k];
            s[i] += v4.x * w[0] + v4.y * w[1] + v4.z * w[2] + v4.w * w[3];
        }
    }
    const float bb = b1[j];
    #pragma unroll
    for (int i = 0; i < 4; i++) { int e = g + 2 * i; d1[e][j] = fmaxf(s[i] + bb, 0.f); }
    __syncthreads();
    const int wv_ = t >> 6, lane = t & 63;
    #pragma unroll
    for (int which = 0; which < 2; which++) {
        int e = 2 * wv_ + which; int n = base + e;
        if (n >= N) continue;
        float a0 = 0.f, a1 = 0.f, a2 = 0.f;
        #pragma unroll
        for (int kk = 0; kk < 2; kk++) {
            int k = lane + 64 * kk;
            float v = d1[e][k];
            a0 += v * w2[k * 3 + 0];
            a1 += v * w2[k * 3 + 1];
            a2 += v * w2[k * 3 + 2];
        }
        #pragma unroll
        for (int m = 32; m >= 1; m >>= 1) {
            a0 += __shfl_xor(a0, m); a1 += __shfl_xor(a1, m); a2 += __shfl_xor(a2, m);
        }
        if (lane == 0) {
            out[(size_t)n * 3 + 0] = a0 + b2[0];
            out[(size_t)n * 3 + 1] = a1 + b2[1];
            out[(size_t)n * 3 + 2] = a2 + b2[2];
        }
    }
}

extern "C" void kernel_launch(void* const* d_in, const int* in_sizes, int n_in,
                              void* d_out, int out_size, void* d_ws, size_t ws_size,
                              hipStream_t stream) {
    const float* x         = (const float*)d_in[0];
    const float* edge_attr = (const float*)d_in[1];
    const int*   ei        = (const int*)d_in[2];
    const float* ne_w1 = (const float*)d_in[3];  const float* ne_b1 = (const float*)d_in[4];
    const float* ne_w2 = (const float*)d_in[5];  const float* ne_b2 = (const float*)d_in[6];
    const float* ne_g  = (const float*)d_in[7];  const float* ne_be = (const float*)d_in[8];
    const float* ee_w1 = (const float*)d_in[9];  const float* ee_b1 = (const float*)d_in[10];
    const float* ee_w2 = (const float*)d_in[11]; const float* ee_b2 = (const float*)d_in[12];
    const float* ee_g  = (const float*)d_in[13]; const float* ee_be = (const float*)d_in[14];
    const float* em_w1 = (const float*)d_in[15]; const float* em_b1 = (const float*)d_in[16];
    const float* em_w2 = (const float*)d_in[17]; const float* em_b2 = (const float*)d_in[18];
    const float* em_g  = (const float*)d_in[19]; const float* em_be = (const float*)d_in[20];
    const float* nm_w1 = (const float*)d_in[21]; const float* nm_b1 = (const float*)d_in[22];
    const float* nm_w2 = (const float*)d_in[23]; const float* nm_b2 = (const float*)d_in[24];
    const float* nm_g  = (const float*)d_in[25]; const float* nm_be = (const float*)d_in[26];
    const float* dec_w1 = (const float*)d_in[27]; const float* dec_b1 = (const float*)d_in[28];
    const float* dec_w2 = (const float*)d_in[29]; const float* dec_b2 = (const float*)d_in[30];

    const int N = in_sizes[0] / 3;
    const int E = in_sizes[2] / 2;

    unsigned short* hA   = (unsigned short*)d_ws;
    unsigned short* hB   = hA + (size_t)N * LAT;
    unsigned short* ebuf = hB + (size_t)N * LAT;
    float*          agg  = (float*)(ebuf + (size_t)E * LAT);
    unsigned short* ew1p = (unsigned short*)(agg + (size_t)N * LAT);
    unsigned short* ew2p = ew1p + 12 * 4096;
    unsigned short* nw1p = ew2p + 4 * 4096;
    unsigned short* nw2p = nw1p + 8 * 4096;
    unsigned short* neW2p = nw2p + 4 * 4096;
    unsigned short* eeW2p = neW2p + 4 * 4096;
    int*            rowtab = (int*)(eeW2p + 4 * 4096);
    int*            coltab = rowtab + 256;

    const dim3 blk(256);

    probe_kernel<<<1, 64, 0, stream>>>(rowtab, coltab);
    pack_w_kernel<<<(12 * 4096 + 255) / 256, blk, 0, stream>>>(em_w1, ew1p, 12);
    pack_w_kernel<<<(4  * 4096 + 255) / 256, blk, 0, stream>>>(em_w2, ew2p, 4);
    pack_w_kernel<<<(8  * 4096 + 255) / 256, blk, 0, stream>>>(nm_w1, nw1p, 8);
    pack_w_kernel<<<(4  * 4096 + 255) / 256, blk, 0, stream>>>(nm_w2, nw2p, 4);
    pack_w_kernel<<<(4  * 4096 + 255) / 256, blk, 0, stream>>>(ne_w2, neW2p, 4);
    pack_w_kernel<<<(4  * 4096 + 255) / 256, blk, 0, stream>>>(ee_w2, eeW2p, 4);

    const int n4 = (N * LAT) / 4;
    zero_kernel<<<(n4 + 255) / 256, blk, 0, stream>>>((float4*)agg, n4);

    const int nb_n32 = (N + EB - 1) / EB;
    const int nb_e32 = (E + EB - 1) / EB;
    encode_hybrid<3><<<nb_n32, blk, 0, stream>>>(x, hA, ne_w1, ne_b1, neW2p, ne_b2,
                                                 ne_g, ne_be, rowtab, coltab, N);
    encode_hybrid<4><<<nb_e32, blk, 0, stream>>>(edge_attr, ebuf, ee_w1, ee_b1, eeW2p, ee_b2,
                                                 ee_g, ee_be, rowtab, coltab, E);

    unsigned short* hc = hA; unsigned short* hn = hB;
    for (int s = 0; s < 5; s++) {
        edge_step_hybrid<<<nb_e32, blk, 0, stream>>>(hc, ebuf, agg, ei,
                                                     ew1p, ew2p, em_b1, em_b2, em_g, em_be,
                                                     rowtab, coltab, E);
        node_step_hybrid<<<nb_n32, blk, 0, stream>>>(agg, hc, hn,
                                                     nw1p, nw2p, nm_b1, nm_b2, nm_g, nm_be,
                                                     rowtab, coltab, N);
        unsigned short* tmp = hc; hc = hn; hn = tmp;
    }
    const int nb_n8 = (N + 7) / 8;
    decode_kernel<<<nb_n8, blk, 0, stream>>>(hc, (float*)d_out, dec_w1, dec_b1, dec_w2, dec_b2, N);
}

// Round 18
// 1632.506 us; speedup vs baseline: 1.0760x; 1.0004x over previous
//
#include <hip/hip_runtime.h>

#define LAT 128
#define LATP 132   // padded fp32 LDS row stride -> reduced-conflict MFMA A-reads
#define EPS 1e-5f
#define EB 32
#define TS 136     // bf16 tile row stride in shorts

typedef __attribute__((ext_vector_type(8))) short bs8;
typedef __attribute__((ext_vector_type(4))) float fx4;

__device__ __forceinline__ float bf2f(unsigned int u) {
    return __uint_as_float(u << 16);
}
__device__ __forceinline__ unsigned short f2bf(float f) {
    unsigned int x = __float_as_uint(f);
    x += 0x7fffu + ((x >> 16) & 1u);   // round-to-nearest-even
    return (unsigned short)(x >> 16);
}
__device__ __forceinline__ void unpack8(uint4 u, float* v) {
    v[0] = bf2f(u.x & 0xffffu); v[1] = bf2f(u.x >> 16);
    v[2] = bf2f(u.y & 0xffffu); v[3] = bf2f(u.y >> 16);
    v[4] = bf2f(u.z & 0xffffu); v[5] = bf2f(u.z >> 16);
    v[6] = bf2f(u.w & 0xffffu); v[7] = bf2f(u.w >> 16);
}
__device__ __forceinline__ uint4 pack8(const float* v) {
    uint4 u;
    u.x = (unsigned)f2bf(v[0]) | ((unsigned)f2bf(v[1]) << 16);
    u.y = (unsigned)f2bf(v[2]) | ((unsigned)f2bf(v[3]) << 16);
    u.z = (unsigned)f2bf(v[4]) | ((unsigned)f2bf(v[5]) << 16);
    u.w = (unsigned)f2bf(v[6]) | ((unsigned)f2bf(v[7]) << 16);
    return u;
}
// fp32 LDS -> bf16 A-fragment (8 consecutive features)
__device__ __forceinline__ bs8 cvt8(const float* p) {
    bs8 r;
    #pragma unroll
    for (int i = 0; i < 8; i++) r[i] = (short)f2bf(p[i]);
    return r;
}

__global__ __launch_bounds__(256) void zero_kernel(float4* __restrict__ p, int n4) {
    int i = blockIdx.x * 256 + threadIdx.x;
    if (i < n4) p[i] = make_float4(0.f, 0.f, 0.f, 0.f);
}

// ---------------------------------------------------------------------------
// C/D-map probe (pi-invariant), VALIDATED round 8.
// ---------------------------------------------------------------------------
__global__ void probe_kernel(int* __restrict__ rowtab, int* __restrict__ coltab) {
    int l = threadIdx.x;
    bs8 idv, ones;
    unsigned short ridb = f2bf((float)(l & 15));
    unsigned short oneb = f2bf(1.f);
    #pragma unroll
    for (int i = 0; i < 8; i++) { idv[i] = (short)ridb; ones[i] = (short)oneb; }
    fx4 dR = {0.f, 0.f, 0.f, 0.f};
    fx4 dC = {0.f, 0.f, 0.f, 0.f};
    dR = __builtin_amdgcn_mfma_f32_16x16x32_bf16(idv, ones, dR, 0, 0, 0);
    dC = __builtin_amdgcn_mfma_f32_16x16x32_bf16(ones, idv, dC, 0, 0, 0);
    #pragma unroll
    for (int reg = 0; reg < 4; reg++) {
        rowtab[l * 4 + reg] = ((int)(dR[reg] * (1.f / 32.f) + 0.5f)) & 15;
        coltab[l * 4 + reg] = ((int)(dC[reg] * (1.f / 32.f) + 0.5f)) & 15;
    }
}

// Pack fp32 weight [K=KS*32][128] into MFMA B-fragment order, bf16. VALIDATED r8.
__global__ __launch_bounds__(256) void pack_w_kernel(
    const float* __restrict__ src, unsigned short* __restrict__ dst, int KS)
{
    int id = blockIdx.x * 256 + threadIdx.x;
    if (id >= KS * 4096) return;
    int j = id & 7;
    int l = (id >> 3) & 63;
    int rest = id >> 9;
    int ks = rest % KS, nt = rest / KS;
    int k = ks * 32 + (l >> 4) * 8 + j;
    int n = nt * 16 + (l & 15);
    dst[id] = f2bf(src[k * 128 + n]);
}

// ---------------------------------------------------------------------------
// HYBRID encoder (r13 validated): VALU L1 -> fp32 LDS -> MFMA L2 -> LN.
// ---------------------------------------------------------------------------
template<int KIN>
__global__ __launch_bounds__(256, 4) void encode_hybrid(
    const float* __restrict__ x, unsigned short* __restrict__ out,
    const float* __restrict__ w1, const float* __restrict__ b1,
    const unsigned short* __restrict__ w2p, const float* __restrict__ b2,
    const float* __restrict__ gam, const float* __restrict__ bet,
    const int* __restrict__ rowtab, const int* __restrict__ coltab, int M)
{
    __shared__ float l1f[EB][LATP];

    const int t = threadIdx.x;
    const int base = blockIdx.x * EB;
    const int j = t & 127, g = t >> 7;

    float wv[KIN];
    #pragma unroll
    for (int u = 0; u < KIN; u++) wv[u] = w1[u * LAT + j];
    const float bb = b1[j];
    #pragma unroll
    for (int i = 0; i < 16; i++) {
        int r = g + 2 * i; int row = base + r;
        float acc = bb;
        if (row < M) {
            #pragma unroll
            for (int u = 0; u < KIN; u++) acc += x[(size_t)row * KIN + u] * wv[u];
        }
        l1f[r][j] = fmaxf(acc, 0.f);
    }
    __syncthreads();

    const int wid = t >> 6, lane = t & 63;
    const int r15 = lane & 15, q = lane >> 4;

    int4 rt = *(const int4*)(rowtab + lane * 4);
    int4 ct = *(const int4*)(coltab + lane * 4);
    int rl4[4] = {rt.x, rt.y, rt.z, rt.w};
    int cl4[4] = {ct.x, ct.y, ct.z, ct.w};

    fx4 a2[2][2];
    #pragma unroll
    for (int mt = 0; mt < 2; mt++)
        #pragma unroll
        for (int nt = 0; nt < 2; nt++) { fx4 z = {0.f, 0.f, 0.f, 0.f}; a2[mt][nt] = z; }

    #pragma unroll
    for (int kc = 0; kc < 4; kc++) {
        bs8 bf0 = *(const bs8*)(w2p + (((size_t)(wid * 2 + 0) * 4 + kc) * 64 + lane) * 8);
        bs8 bf1 = *(const bs8*)(w2p + (((size_t)(wid * 2 + 1) * 4 + kc) * 64 + lane) * 8);
        #pragma unroll
        for (int mt = 0; mt < 2; mt++) {
            int row = mt * 16 + r15;
            int k0 = kc * 32 + q * 8;
            bs8 a = cvt8(&l1f[row][k0]);
            a2[mt][0] = __builtin_amdgcn_mfma_f32_16x16x32_bf16(a, bf0, a2[mt][0], 0, 0, 0);
            a2[mt][1] = __builtin_amdgcn_mfma_f32_16x16x32_bf16(a, bf1, a2[mt][1], 0, 0, 0);
        }
    }
    __syncthreads();

    #pragma unroll
    for (int nt = 0; nt < 2; nt++) {
        #pragma unroll
        for (int reg = 0; reg < 4; reg++) {
            int cg = (wid * 2 + nt) * 16 + cl4[reg];
            float bv = b2[cg];
            #pragma unroll
            for (int mt = 0; mt < 2; mt++) {
                int row = mt * 16 + rl4[reg];
                l1f[row][cg] = fmaxf(a2[mt][nt][reg] + bv, 0.f);
            }
        }
    }
    __syncthreads();

    const float g0 = gam[lane], g1 = gam[lane + 64];
    const float be0 = bet[lane], be1 = bet[lane + 64];
    #pragma unroll
    for (int which = 0; which < 8; which++) {
        int row = wid * 8 + which;
        int rowg = base + row;
        float v0 = l1f[row][lane], v1 = l1f[row][lane + 64];
        float s1 = v0 + v1, sq = v0 * v0 + v1 * v1;
        #pragma unroll
        for (int m = 32; m >= 1; m >>= 1) { s1 += __shfl_xor(s1, m); sq += __shfl_xor(sq, m); }
        float mu = s1 * (1.f / LAT);
        float var = sq * (1.f / LAT) - mu * mu;
        float inv = rsqrtf(var + EPS);
        if (rowg < M) {
            out[(size_t)rowg * LAT + lane]      = f2bf((v0 - mu) * inv * g0 + be0);
            out[(size_t)rowg * LAT + lane + 64] = f2bf((v1 - mu) * inv * g1 + be1);
        }
    }
}

// ---------------------------------------------------------------------------
// Edge step (r13 validated): LDS union (hd/hs -> l1m/l1n) -> 34KB -> 4 blk/CU.
// ev direct from global. MFMA L1 dual + MFMA L2 (cvt8).
// ---------------------------------------------------------------------------
__global__ __launch_bounds__(256, 4) void edge_step_hybrid(
    const unsigned short* __restrict__ h, unsigned short* __restrict__ e_buf,
    float* __restrict__ agg, const int* __restrict__ ei,
    const unsigned short* __restrict__ w1p, const unsigned short* __restrict__ w2p,
    const float* __restrict__ b1, const float* __restrict__ b2,
    const float* __restrict__ gam, const float* __restrict__ bet,
    const int* __restrict__ rowtab, const int* __restrict__ coltab, int E)
{
    __shared__ __align__(16) float poolf[2 * EB * LATP];   // 33.8KB union
    __shared__ int sd[EB], ss[EB];
    unsigned short* hd = (unsigned short*)poolf;
    unsigned short* hs = (unsigned short*)poolf + EB * TS;
    float (*l1m)[LATP] = (float(*)[LATP])poolf;
    float (*l1n)[LATP] = (float(*)[LATP])(poolf + EB * LATP);

    const int t = threadIdx.x;
    const int base = blockIdx.x * EB;
    if (t < EB) {
        int ge = base + t;
        sd[t] = (ge < E) ? ei[E + ge] : 0;  // dst
        ss[t] = (ge < E) ? ei[ge] : 0;      // src
    }
    __syncthreads();

    for (int idx = t; idx < 2 * EB * 16; idx += 256) {
        int seg = idx / (EB * 16);
        int rem = idx - seg * (EB * 16);
        int r = rem >> 4, c = rem & 15;
        int ge = base + r;
        uint4 v = make_uint4(0, 0, 0, 0);
        if (ge < E) {
            const unsigned short* src = h + (size_t)(seg == 0 ? sd[r] : ss[r]) * LAT;
            v = *(const uint4*)(src + c * 8);
        }
        unsigned short* dstT = (seg == 0) ? hd : hs;
        *(uint4*)&dstT[r * TS + c * 8] = v;
    }
    __syncthreads();

    const int wid = t >> 6, lane = t & 63;
    const int r15 = lane & 15, q = lane >> 4;

    int4 rt = *(const int4*)(rowtab + lane * 4);
    int4 ct = *(const int4*)(coltab + lane * 4);
    int rl4[4] = {rt.x, rt.y, rt.z, rt.w};
    int cl4[4] = {ct.x, ct.y, ct.z, ct.w};

    // ---- MFMA layer 1, dual accumulators, shared ev@WB (ev from global) ----
    fx4 accm[2][2], accn[2][2];
    #pragma unroll
    for (int mt = 0; mt < 2; mt++)
        #pragma unroll
        for (int nt = 0; nt < 2; nt++) { fx4 z = {0.f, 0.f, 0.f, 0.f}; accm[mt][nt] = z; }

    #pragma unroll
    for (int kc = 0; kc < 4; kc++) {
        int ks = 8 + kc;
        bs8 bf0 = *(const bs8*)(w1p + (((size_t)(wid * 2 + 0) * 12 + ks) * 64 + lane) * 8);
        bs8 bf1 = *(const bs8*)(w1p + (((size_t)(wid * 2 + 1) * 12 + ks) * 64 + lane) * 8);
        #pragma unroll
        for (int mt = 0; mt < 2; mt++) {
            bs8 ae = *(const bs8*)(e_buf + (size_t)(base + mt * 16 + r15) * LAT + kc * 32 + q * 8);
            accm[mt][0] = __builtin_amdgcn_mfma_f32_16x16x32_bf16(ae, bf0, accm[mt][0], 0, 0, 0);
            accm[mt][1] = __builtin_amdgcn_mfma_f32_16x16x32_bf16(ae, bf1, accm[mt][1], 0, 0, 0);
        }
    }
    #pragma unroll
    for (int mt = 0; mt < 2; mt++) { accn[mt][0] = accm[mt][0]; accn[mt][1] = accm[mt][1]; }

    #pragma unroll
    for (int ts = 0; ts < 2; ts++) {
        const unsigned short* tA = ts ? hs : hd;
        const unsigned short* tB = ts ? hd : hs;
        #pragma unroll
        for (int kc = 0; kc < 4; kc++) {
            int ks = ts * 4 + kc;
            bs8 bf0 = *(const bs8*)(w1p + (((size_t)(wid * 2 + 0) * 12 + ks) * 64 + lane) * 8);
            bs8 bf1 = *(const bs8*)(w1p + (((size_t)(wid * 2 + 1) * 12 + ks) * 64 + lane) * 8);
            #pragma unroll
            for (int mt = 0; mt < 2; mt++) {
                int aoff = (mt * 16 + r15) * TS + kc * 32 + q * 8;
                bs8 am = *(const bs8*)(tA + aoff);
                bs8 an = *(const bs8*)(tB + aoff);
                accm[mt][0] = __builtin_amdgcn_mfma_f32_16x16x32_bf16(am, bf0, accm[mt][0], 0, 0, 0);
                accm[mt][1] = __builtin_amdgcn_mfma_f32_16x16x32_bf16(am, bf1, accm[mt][1], 0, 0, 0);
                accn[mt][0] = __builtin_amdgcn_mfma_f32_16x16x32_bf16(an, bf0, accn[mt][0], 0, 0, 0);
                accn[mt][1] = __builtin_amdgcn_mfma_f32_16x16x32_bf16(an, bf1, accn[mt][1], 0, 0, 0);
            }
        }
    }
    __syncthreads();   // UNION: all reads of hd/hs done before l1m/l1n writes

    #pragma unroll
    for (int nt = 0; nt < 2; nt++) {
        #pragma unroll
        for (int reg = 0; reg < 4; reg++) {
            int cg = (wid * 2 + nt) * 16 + cl4[reg];
            float bv = b1[cg];
            #pragma unroll
            for (int mt = 0; mt < 2; mt++) {
                int row = mt * 16 + rl4[reg];
                l1m[row][cg] = fmaxf(accm[mt][nt][reg] + bv, 0.f);
                l1n[row][cg] = fmaxf(accn[mt][nt][reg] + bv, 0.f);
            }
        }
    }
    __syncthreads();

    // ---- MFMA layer 2: A = cvt8(fp32 l1), B = w2p (KS=4) ----
    fx4 a2m[2][2], a2n[2][2];
    #pragma unroll
    for (int mt = 0; mt < 2; mt++)
        #pragma unroll
        for (int nt = 0; nt < 2; nt++) { fx4 z = {0.f, 0.f, 0.f, 0.f}; a2m[mt][nt] = z; a2n[mt][nt] = z; }

    #pragma unroll
    for (int kc = 0; kc < 4; kc++) {
        bs8 bf0 = *(const bs8*)(w2p + (((size_t)(wid * 2 + 0) * 4 + kc) * 64 + lane) * 8);
        bs8 bf1 = *(const bs8*)(w2p + (((size_t)(wid * 2 + 1) * 4 + kc) * 64 + lane) * 8);
        #pragma unroll
        for (int mt = 0; mt < 2; mt++) {
            int row = mt * 16 + r15;
            int k0 = kc * 32 + q * 8;
            bs8 am = cvt8(&l1m[row][k0]);
            bs8 an = cvt8(&l1n[row][k0]);
            a2m[mt][0] = __builtin_amdgcn_mfma_f32_16x16x32_bf16(am, bf0, a2m[mt][0], 0, 0, 0);
            a2m[mt][1] = __builtin_amdgcn_mfma_f32_16x16x32_bf16(am, bf1, a2m[mt][1], 0, 0, 0);
            a2n[mt][0] = __builtin_amdgcn_mfma_f32_16x16x32_bf16(an, bf0, a2n[mt][0], 0, 0, 0);
            a2n[mt][1] = __builtin_amdgcn_mfma_f32_16x16x32_bf16(an, bf1, a2n[mt][1], 0, 0, 0);
        }
    }
    __syncthreads();

    #pragma unroll
    for (int nt = 0; nt < 2; nt++) {
        #pragma unroll
        for (int reg = 0; reg < 4; reg++) {
            int cg = (wid * 2 + nt) * 16 + cl4[reg];
            float bv = b2[cg];
            #pragma unroll
            for (int mt = 0; mt < 2; mt++) {
                int row = mt * 16 + rl4[reg];
                l1m[row][cg] = fmaxf(a2m[mt][nt][reg] + bv, 0.f);
                l1n[row][cg] = fmaxf(a2n[mt][nt][reg] + bv, 0.f);
            }
        }
    }
    __syncthreads();

    // ---- LN epilogue (proven dual pattern), 8 rows per wave ----
    const float g0 = gam[lane], g1 = gam[lane + 64];
    const float be0 = bet[lane], be1 = bet[lane + 64];
    #pragma unroll
    for (int which = 0; which < 8; which++) {
        int row = wid * 8 + which;
        int ge = base + row;
        float v0 = l1m[row][lane], v1 = l1m[row][lane + 64];
        float u0 = l1n[row][lane], u1 = l1n[row][lane + 64];
        float s1m = v0 + v1, sqm = v0 * v0 + v1 * v1;
        float s1n = u0 + u1, sqn = u0 * u0 + u1 * u1;
        #pragma unroll
        for (int m = 32; m >= 1; m >>= 1) {
            s1m += __shfl_xor(s1m, m); sqm += __shfl_xor(sqm, m);
            s1n += __shfl_xor(s1n, m); sqn += __shfl_xor(sqn, m);
        }
        float mum = s1m * (1.f / LAT), varm = sqm * (1.f / LAT) - mum * mum;
        float mun = s1n * (1.f / LAT), varn = sqn * (1.f / LAT) - mun * mun;
        float im = rsqrtf(varm + EPS), in_ = rsqrtf(varn + EPS);
        if (ge < E) {
            int dn = sd[row];
            atomicAdd(&agg[(size_t)dn * LAT + lane],      (v0 - mum) * im * g0 + be0);
            atomicAdd(&agg[(size_t)dn * LAT + lane + 64], (v1 - mum) * im * g1 + be1);
            float e0 = bf2f(e_buf[(size_t)ge * LAT + lane]);
            float e1 = bf2f(e_buf[(size_t)ge * LAT + lane + 64]);
            e_buf[(size_t)ge * LAT + lane]      = f2bf((u0 - mun) * in_ * g0 + be0 + e0);
            e_buf[(size_t)ge * LAT + lane + 64] = f2bf((u1 - mun) * in_ * g1 + be1 + e1);
        }
    }
}

// ---------------------------------------------------------------------------
// Node step (r13 validated): MFMA L1 + MFMA L2 (cvt8), single fp32 LDS buffer.
// ---------------------------------------------------------------------------
__global__ __launch_bounds__(256, 4) void node_step_hybrid(
    float* __restrict__ agg, const unsigned short* __restrict__ h,
    unsigned short* __restrict__ h_out,
    const unsigned short* __restrict__ w1p, const unsigned short* __restrict__ w2p,
    const float* __restrict__ b1, const float* __restrict__ b2,
    const float* __restrict__ gam, const float* __restrict__ bet,
    const int* __restrict__ rowtab, const int* __restrict__ coltab, int N)
{
    __shared__ __align__(16) unsigned short aT[EB * TS];
    __shared__ __align__(16) unsigned short hT[EB * TS];
    __shared__ float l1f[EB][LATP];

    const int t = threadIdx.x;
    const int base = blockIdx.x * EB;

    for (int idx = t; idx < EB * 16; idx += 256) {
        int r = idx >> 4, c = idx & 15;
        int n = base + r;
        if (n < N) {
            float* ap = agg + (size_t)n * LAT + c * 8;
            float4 f0 = *(float4*)ap;
            float4 f1 = *(float4*)(ap + 4);
            float av[8] = {f0.x, f0.y, f0.z, f0.w, f1.x, f1.y, f1.z, f1.w};
            *(uint4*)&aT[r * TS + c * 8] = pack8(av);
            *(float4*)ap = make_float4(0.f, 0.f, 0.f, 0.f);
            *(float4*)(ap + 4) = make_float4(0.f, 0.f, 0.f, 0.f);
            *(uint4*)&hT[r * TS + c * 8] = *(const uint4*)(h + (size_t)n * LAT + c * 8);
        } else {
            uint4 z = make_uint4(0, 0, 0, 0);
            *(uint4*)&aT[r * TS + c * 8] = z;
            *(uint4*)&hT[r * TS + c * 8] = z;
        }
    }
    __syncthreads();

    const int wid = t >> 6, lane = t & 63;
    const int r15 = lane & 15, q = lane >> 4;

    int4 rt = *(const int4*)(rowtab + lane * 4);
    int4 ct = *(const int4*)(coltab + lane * 4);
    int rl4[4] = {rt.x, rt.y, rt.z, rt.w};
    int cl4[4] = {ct.x, ct.y, ct.z, ct.w};

    fx4 acc[2][2];
    #pragma unroll
    for (int mt = 0; mt < 2; mt++)
        #pragma unroll
        for (int nt = 0; nt < 2; nt++) { fx4 z = {0.f, 0.f, 0.f, 0.f}; acc[mt][nt] = z; }

    #pragma unroll
    for (int ts = 0; ts < 2; ts++) {
        const unsigned short* tA = ts ? hT : aT;
        #pragma unroll
        for (int kc = 0; kc < 4; kc++) {
            int ks = ts * 4 + kc;
            bs8 bf0 = *(const bs8*)(w1p + (((size_t)(wid * 2 + 0) * 8 + ks) * 64 + lane) * 8);
            bs8 bf1 = *(const bs8*)(w1p + (((size_t)(wid * 2 + 1) * 8 + ks) * 64 + lane) * 8);
            #pragma unroll
            for (int mt = 0; mt < 2; mt++) {
                bs8 a = *(const bs8*)(tA + (mt * 16 + r15) * TS + kc * 32 + q * 8);
                acc[mt][0] = __builtin_amdgcn_mfma_f32_16x16x32_bf16(a, bf0, acc[mt][0], 0, 0, 0);
                acc[mt][1] = __builtin_amdgcn_mfma_f32_16x16x32_bf16(a, bf1, acc[mt][1], 0, 0, 0);
            }
        }
    }
    #pragma unroll
    for (int nt = 0; nt < 2; nt++) {
        #pragma unroll
        for (int reg = 0; reg < 4; reg++) {
            int cg = (wid * 2 + nt) * 16 + cl4[reg];
            float bv = b1[cg];
            #pragma unroll
            for (int mt = 0; mt < 2; mt++) {
                int row = mt * 16 + rl4[reg];
                l1f[row][cg] = fmaxf(acc[mt][nt][reg] + bv, 0.f);
            }
        }
    }
    __syncthreads();

    fx4 a2[2][2];
    #pragma unroll
    for (int mt = 0; mt < 2; mt++)
        #pragma unroll
        for (int nt = 0; nt < 2; nt++) { fx4 z = {0.f, 0.f, 0.f, 0.f}; a2[mt][nt] = z; }

    #pragma unroll
    for (int kc = 0; kc < 4; kc++) {
        bs8 bf0 = *(const bs8*)(w2p + (((size_t)(wid * 2 + 0) * 4 + kc) * 64 + lane) * 8);
        bs8 bf1 = *(const bs8*)(w2p + (((size_t)(wid * 2 + 1) * 4 + kc) * 64 + lane) * 8);
        #pragma unroll
        for (int mt = 0; mt < 2; mt++) {
            int row = mt * 16 + r15;
            int k0 = kc * 32 + q * 8;
            bs8 a = cvt8(&l1f[row][k0]);
            a2[mt][0] = __builtin_amdgcn_mfma_f32_16x16x32_bf16(a, bf0, a2[mt][0], 0, 0, 0);
            a2[mt][1] = __builtin_amdgcn_mfma_f32_16x16x32_bf16(a, bf1, a2[mt][1], 0, 0, 0);
        }
    }
    __syncthreads();

    #pragma unroll
    for (int nt = 0; nt < 2; nt++) {
        #pragma unroll
        for (int reg = 0; reg < 4; reg++) {
            int cg = (wid * 2 + nt) * 16 + cl4[reg];
            float bv = b2[cg];
            #pragma unroll
            for (int mt = 0; mt < 2; mt++) {
                int row = mt * 16 + rl4[reg];
                l1f[row][cg] = fmaxf(a2[mt][nt][reg] + bv, 0.f);
            }
        }
    }
    __syncthreads();

    const float g0 = gam[lane], g1 = gam[lane + 64];
    const float be0 = bet[lane], be1 = bet[lane + 64];
    #pragma unroll
    for (int which = 0; which < 8; which++) {
        int row = wid * 8 + which;
        int n = base + row;
        float v0 = l1f[row][lane], v1 = l1f[row][lane + 64];
        float s1 = v0 + v1, sq = v0 * v0 + v1 * v1;
        #pragma unroll
        for (int m = 32; m >= 1; m >>= 1) { s1 += __shfl_xor(s1, m); sq += __shfl_xor(sq, m); }
        float mu = s1 * (1.f / LAT);
        float var = sq * (1.f / LAT) - mu * mu;
        float inv = rsqrtf(var + EPS);
        if (n < N) {
            float h0 = bf2f(hT[row * TS + lane]);
            float h1 = bf2f(hT[row * TS + lane + 64]);
            h_out[(size_t)n * LAT + lane]      = f2bf((v0 - mu) * inv * g0 + be0 + h0);
            h_out[(size_t)n * LAT + lane + 64] = f2bf((v1 - mu) * inv * g1 + be1 + h1);
        }
    }
}

// ---------------------------------------------------------------------------
// Decoder (PROVEN)
// ---------------------------------------------------------------------------
__global__ __launch_bounds__(256) void decode_kernel(
    const unsigned short* __restrict__ h, float* __restrict__ out,
    const float* __restrict__ w1, const float* __restrict__ b1,
    const float* __restrict__ w2, const float* __restrict__ b2, int N)
{
    __shared__ float hv[8][LAT], d1[8][LAT];
    const int t = threadIdx.x;
    const int base = blockIdx.x * 8;
    for (int idx = t; idx < 8 * 16; idx += 256) {
        int e = idx >> 4; int c8 = (idx & 15) * 8;
        int n = base + e;
        float v[8];
        for (int u = 0; u < 8; u++) v[u] = 0.f;
        if (n < N) unpack8(*(const uint4*)(h + (size_t)n * LAT + c8), v);
        for (int u = 0; u < 8; u++) hv[e][c8 + u] = v[u];
    }
    __syncthreads();
    const int j = t & 127, g = t >> 7;
    float s[4] = {0, 0, 0, 0};
    for (int k = 0; k < LAT; k += 4) {
        float w[4];
        #pragma unroll
        for (int u = 0; u < 4; u++) w[u] = w1[(k + u) * LAT + j];
        #pragma unroll
        for (int i = 0; i < 4; i++) {
            int e = g + 2 * i;
            float4 v4 = *(const float4*)&hv[e][k];
            s[i] += v4.x * w[0] + v4.y * w[1] + v4.z * w[2] + v4.w * w[3];
        }
    }
    const float bb = b1[j];
    #pragma unroll
    for (int i = 0; i < 4; i++) { int e = g + 2 * i; d1[e][j] = fmaxf(s[i] + bb, 0.f); }
    __syncthreads();
    const int wv_ = t >> 6, lane = t & 63;
    #pragma unroll
    for (int which = 0; which < 2; which++) {
        int e = 2 * wv_ + which; int n = base + e;
        if (n >= N) continue;
        float a0 = 0.f, a1 = 0.f, a2 = 0.f;
        #pragma unroll
        for (int kk = 0; kk < 2; kk++) {
            int k = lane + 64 * kk;
            float v = d1[e][k];
            a0 += v * w2[k * 3 + 0];
            a1 += v * w2[k * 3 + 1];
            a2 += v * w2[k * 3 + 2];
        }
        #pragma unroll
        for (int m = 32; m >= 1; m >>= 1) {
            a0 += __shfl_xor(a0, m); a1 += __shfl_xor(a1, m); a2 += __shfl_xor(a2, m);
        }
        if (lane == 0) {
            out[(size_t)n * 3 + 0] = a0 + b2[0];
            out[(size_t)n * 3 + 1] = a1 + b2[1];
            out[(size_t)n * 3 + 2] = a2 + b2[2];
        }
    }
}

extern "C" void kernel_launch(void* const* d_in, const int* in_sizes, int n_in,
                              void* d_out, int out_size, void* d_ws, size_t ws_size,
                              hipStream_t stream) {
    const float* x         = (const float*)d_in[0];
    const float* edge_attr = (const float*)d_in[1];
    const int*   ei        = (const int*)d_in[2];
    const float* ne_w1 = (const float*)d_in[3];  const float* ne_b1 = (const float*)d_in[4];
    const float* ne_w2 = (const float*)d_in[5];  const float* ne_b2 = (const float*)d_in[6];
    const float* ne_g  = (const float*)d_in[7];  const float* ne_be = (const float*)d_in[8];
    const float* ee_w1 = (const float*)d_in[9];  const float* ee_b1 = (const float*)d_in[10];
    const float* ee_w2 = (const float*)d_in[11]; const float* ee_b2 = (const float*)d_in[12];
    const float* ee_g  = (const float*)d_in[13]; const float* ee_be = (const float*)d_in[14];
    const float* em_w1 = (const float*)d_in[15]; const float* em_b1 = (const float*)d_in[16];
    const float* em_w2 = (const float*)d_in[17]; const float* em_b2 = (const float*)d_in[18];
    const float* em_g  = (const float*)d_in[19]; const float* em_be = (const float*)d_in[20];
    const float* nm_w1 = (const float*)d_in[21]; const float* nm_b1 = (const float*)d_in[22];
    const float* nm_w2 = (const float*)d_in[23]; const float* nm_b2 = (const float*)d_in[24];
    const float* nm_g  = (const float*)d_in[25]; const float* nm_be = (const float*)d_in[26];
    const float* dec_w1 = (const float*)d_in[27]; const float* dec_b1 = (const float*)d_in[28];
    const float* dec_w2 = (const float*)d_in[29]; const float* dec_b2 = (const float*)d_in[30];

    const int N = in_sizes[0] / 3;
    const int E = in_sizes[2] / 2;

    unsigned short* hA   = (unsigned short*)d_ws;
    unsigned short* hB   = hA + (size_t)N * LAT;
    unsigned short* ebuf = hB + (size_t)N * LAT;
    float*          agg  = (float*)(ebuf + (size_t)E * LAT);
    unsigned short* ew1p = (unsigned short*)(agg + (size_t)N * LAT);
    unsigned short* ew2p = ew1p + 12 * 4096;
    unsigned short* nw1p = ew2p + 4 * 4096;
    unsigned short* nw2p = nw1p + 8 * 4096;
    unsigned short* neW2p = nw2p + 4 * 4096;
    unsigned short* eeW2p = neW2p + 4 * 4096;
    int*            rowtab = (int*)(eeW2p + 4 * 4096);
    int*            coltab = rowtab + 256;

    const dim3 blk(256);

    probe_kernel<<<1, 64, 0, stream>>>(rowtab, coltab);
    pack_w_kernel<<<(12 * 4096 + 255) / 256, blk, 0, stream>>>(em_w1, ew1p, 12);
    pack_w_kernel<<<(4  * 4096 + 255) / 256, blk, 0, stream>>>(em_w2, ew2p, 4);
    pack_w_kernel<<<(8  * 4096 + 255) / 256, blk, 0, stream>>>(nm_w1, nw1p, 8);
    pack_w_kernel<<<(4  * 4096 + 255) / 256, blk, 0, stream>>>(nm_w2, nw2p, 4);
    pack_w_kernel<<<(4  * 4096 + 255) / 256, blk, 0, stream>>>(ne_w2, neW2p, 4);
    pack_w_kernel<<<(4  * 4096 + 255) / 256, blk, 0, stream>>>(ee_w2, eeW2p, 4);

    const int n4 = (N * LAT) / 4;
    zero_kernel<<<(n4 + 255) / 256, blk, 0, stream>>>((float4*)agg, n4);

    const int nb_n32 = (N + EB - 1) / EB;
    const int nb_e32 = (E + EB - 1) / EB;
    encode_hybrid<3><<<nb_n32, blk, 0, stream>>>(x, hA, ne_w1, ne_b1, neW2p, ne_b2,
                                                 ne_g, ne_be, rowtab, coltab, N);
    encode_hybrid<4><<<nb_e32, blk, 0, stream>>>(edge_attr, ebuf, ee_w1, ee_b1, eeW2p, ee_b2,
                                                 ee_g, ee_be, rowtab, coltab, E);

    unsigned short* hc = hA; unsigned short* hn = hB;
    for (int s = 0; s < 5; s++) {
        edge_step_hybrid<<<nb_e32, blk, 0, stream>>>(hc, ebuf, agg, ei,
                                                     ew1p, ew2p, em_b1, em_b2, em_g, em_be,
                                                     rowtab, coltab, E);
        node_step_hybrid<<<nb_n32, blk, 0, stream>>>(agg, hc, hn,
                                                     nw1p, nw2p, nm_b1, nm_b2, nm_g, nm_be,
                                                     rowtab, coltab, N);
        unsigned short* tmp = hc; hc = hn; hn = tmp;
    }
    const int nb_n8 = (N + 7) / 8;
    decode_kernel<<<nb_n8, blk, 0, stream>>>(hc, (float*)d_out, dec_w1, dec_b1, dec_w2, dec_b2, N);
}